// Round 1
// 531.871 us; speedup vs baseline: 1.3112x; 1.3112x over previous
//
#include <hip/hip_runtime.h>
#include <hip/hip_bf16.h>

#define Hh 56
#define Ww 56
#define Cc 256
#define Tt 16
#define Bb 4
#define Nn 3136
#define Kk 784
#define KX 28
#define Dd 128
#define Mc 64
#define NTOP 32

// ---------------- K3a: combined weight Wc^T [c][d] and bias bc ---------------
__global__ __launch_bounds__(128) void k_wc(
    const float* __restrict__ pw_w, const float* __restrict__ pw_b,
    const float* __restrict__ proj_w, const float* __restrict__ proj_b,
    float* __restrict__ wct, float* __restrict__ bc) {
  int c = blockIdx.x;
  int d = threadIdx.x;
  float acc = 0.f;
  for (int m = 0; m < Mc; ++m) acc += proj_w[d * Mc + m] * pw_w[m * Cc + c];
  wct[c * Dd + d] = acc;
  if (c == 0) {
    float bb = proj_b[d];
    for (int m = 0; m < Mc; ++m) bb += proj_w[d * Mc + m] * pw_b[m];
    bc[d] = bb;
  }
}

// ---- K_mix: y[b][d][n] = sum_c fm[b][c][n] * wct[c][d]  (channel mix FIRST;
//      commutes with warp+pool since those are per-channel spatial linear ops)
// grid: b(4) x ntile(112 of 28) = 448 blocks, 256 thr
__global__ __launch_bounds__(256) void k_mix(
    const float* __restrict__ fm, const float* __restrict__ wct, float* __restrict__ y) {
  int blk = blockIdx.x;
  int b = blk / 112;
  int n0 = (blk % 112) * 28;
  int tid = threadIdx.x;
  int d = tid & 127;
  int ng = tid >> 7;               // 0..1
  __shared__ float fm_s[64 * 28];
  __shared__ float wc_s[64 * Dd];
  float acc[14];
#pragma unroll
  for (int j = 0; j < 14; ++j) acc[j] = 0.f;
  const float* fb = fm + (size_t)b * Cc * Nn;
  for (int c0 = 0; c0 < Cc; c0 += 64) {
    for (int i = tid; i < 64 * 28; i += 256) {
      int c = i / 28, kx = i - c * 28;
      fm_s[i] = fb[(size_t)(c0 + c) * Nn + n0 + kx];
    }
    for (int i = tid; i < 64 * Dd; i += 256) wc_s[i] = wct[c0 * Dd + i];
    __syncthreads();
    for (int c = 0; c < 64; ++c) {
      float w = wc_s[c * Dd + d];
#pragma unroll
      for (int j = 0; j < 14; ++j) acc[j] += fm_s[c * 28 + ng * 14 + j] * w;
    }
    __syncthreads();
  }
  float* yo = y + ((size_t)b * Dd + d) * Nn + n0 + ng * 14;
#pragma unroll
  for (int j = 0; j < 14; ++j) yo[j] = acc[j];
}

// ---- K1: fused affine warp + bilinear + 9x9/s2 zero-pad avg-pool on mixed y
//      writes z[(tb*K + k)*D + d] = pooled + bc[d]  (k_zgemm eliminated)
// grid: b(4) x dg(32 of 4 d) x t(16) = 2048 blocks, 256 thr
// No fm staging: 4 bilinear taps read straight from global; y (6.4 MB) is
// L2-resident and near-identity warp keeps lanes coalesced. LDS = 18.8 KB
// -> 8 blocks/CU (was 69 KB -> 2 blocks/CU).
__global__ __launch_bounds__(256) void k_fused_pool(
    const float* __restrict__ y, const float* __restrict__ Abank,
    const float* __restrict__ bc, float* __restrict__ z) {
  int idx = blockIdx.x;
  int b = idx & 3;
  int dg = (idx >> 2) & 31;
  int t = idx >> 7;
  __shared__ float wsm[3136];
  __shared__ float rowp[1568];
  int tid = threadIdx.x;
  const float* A = Abank + t * 6;
  float a00 = A[0], a01 = A[1], a02 = A[2], a10 = A[3], a11 = A[4], a12 = A[5];
  // per-thread coords for its ~13 pixels (t-dependent only, reused for 4 d)
  int off[13];
  float wxa[13], wya[13];
#pragma unroll
  for (int j = 0; j < 13; ++j) {
    int e = tid + 256 * j;
    if (e < 3136) {
      int h = e / 56, w = e - h * 56;
      float gx = (2.0f * w + 1.0f) / 56.0f - 1.0f;
      float gy = (2.0f * h + 1.0f) / 56.0f - 1.0f;
      float u = a00 * gx + a01 * gy + a02;
      float v = a10 * gx + a11 * gy + a12;
      float ix = ((u + 1.0f) * 56.0f - 1.0f) * 0.5f;
      float iy = ((v + 1.0f) * 56.0f - 1.0f) * 0.5f;
      float x0f = floorf(ix), y0f = floorf(iy);
      wxa[j] = ix - x0f;
      wya[j] = iy - y0f;
      int x0 = (int)x0f, y0 = (int)y0f;
      int x0c = min(max(x0, 0), 55), x1c = min(max(x0 + 1, 0), 55);
      int y0c = min(max(y0, 0), 55), y1c = min(max(y0 + 1, 0), 55);
      off[j] = (y0c * 56 + x0c) | ((x1c - x0c) << 12) | ((y1c - y0c) << 13);
    }
  }
  for (int dd = 0; dd < 4; ++dd) {
    int d = dg * 4 + dd;
    const float* fc = y + ((size_t)b * Dd + d) * Nn;
    float bias = bc[d];
    // stage A: warped -> wsm (taps from global, cache-served)
#pragma unroll
    for (int j = 0; j < 13; ++j) {
      int e = tid + 256 * j;
      if (e < 3136) {
        int pk = off[j];
        int base = pk & 4095;
        int dx = (pk >> 12) & 1;
        int dyy = (pk & (1 << 13)) ? 56 : 0;
        float v00 = fc[base], v01 = fc[base + dx];
        float v10 = fc[base + dyy], v11 = fc[base + dyy + dx];
        float wx = wxa[j], wy = wya[j];
        float top = v00 + wx * (v01 - v00);
        float bot = v10 + wx * (v11 - v10);
        wsm[e] = top + wy * (bot - top);
      }
    }
    __syncthreads();
    // stage B: row pool (horizontal 9, stride 2) -> rowp[56][28]
    for (int e = tid; e < 1568; e += 256) {
      int h = e / 28, kx = e - h * 28;
      int xs = 2 * kx - 4;
      int lo = max(xs, 0), hi = min(xs + 8, 55);
      float s = 0.f;
      const float* wr = wsm + h * 56;
      for (int x = lo; x <= hi; ++x) s += wr[x];
      rowp[e] = s;
    }
    __syncthreads();
    // stage C: col pool (vertical 9, stride 2) -> z (+bias), d-strided scatter
    float* zo = z + (size_t)(t * Bb + b) * Kk * Dd + d;
    for (int e = tid; e < 784; e += 256) {
      int ky = e / 28, kx = e - ky * 28;
      int ys = 2 * ky - 4;
      int lo = max(ys, 0), hi = min(ys + 8, 55);
      float s = 0.f;
      for (int h = lo; h <= hi; ++h) s += rowp[h * 28 + kx];
      zo[(size_t)e * Dd] = s * (1.0f / 81.0f) + bias;
    }
    __syncthreads();
  }
}

// ---------------- K4: normalize z rows, s = zn . r ---------------------------
__global__ __launch_bounds__(256) void k_znorm(
    float* __restrict__ z, const float* __restrict__ r, float* __restrict__ s_arr) {
  int row = blockIdx.x * 4 + (threadIdx.x >> 6);
  int lane = threadIdx.x & 63;
  float* zr = z + (size_t)row * Dd;
  float z0 = zr[lane], z1 = zr[lane + 64];
  float ss = z0 * z0 + z1 * z1;
  for (int off = 32; off; off >>= 1) ss += __shfl_xor(ss, off);
  float inv = 1.0f / fmaxf(sqrtf(ss), 1e-6f);
  z0 *= inv; z1 *= inv;
  zr[lane] = z0; zr[lane + 64] = z1;
  float sd = z0 * r[lane] + z1 * r[lane + 64];
  for (int off = 32; off; off >>= 1) sd += __shfl_xor(sd, off);
  if (lane == 0) s_arr[row] = sd;
}

// ---------------- K5: softmax over T, g_emb ----------------------------------
__global__ __launch_bounds__(128) void k_gemb(
    const float* __restrict__ z, const float* __restrict__ s_arr, float* __restrict__ g) {
  int blk = blockIdx.x;            // b*784 + k
  int b = blk / Kk, k = blk % Kk;
  int d = threadIdx.x;
  float sv[Tt];
  float mx = -3.4e38f;
#pragma unroll
  for (int t = 0; t < Tt; ++t) {
    sv[t] = s_arr[(t * Bb + b) * Kk + k];
    mx = fmaxf(mx, sv[t]);
  }
  float sum = 0.f;
#pragma unroll
  for (int t = 0; t < Tt; ++t) {
    sv[t] = expf(10.0f * (sv[t] - mx));
    sum += sv[t];
  }
  float isum = 1.0f / sum;
  float acc = 0.f;
#pragma unroll
  for (int t = 0; t < Tt; ++t)
    acc += sv[t] * isum * z[((size_t)(t * Bb + b) * Kk + k) * Dd + d];
  g[((size_t)b * Kk + k) * Dd + d] = acc;
}

// ---------------- K6: E = normalize(M @ g) via sparse bilinear structure -----
__global__ __launch_bounds__(64) void k_E(
    const float* __restrict__ Mmat, const float* __restrict__ g, float* __restrict__ E) {
  int row = blockIdx.x;            // b*N + n
  int b = row / Nn, n = row % Nn;
  int y = n / Ww, x = n % Ww;
  int x0 = x >> 1, y0 = y >> 1;
  int x1 = min(x0 + 1, 27), y1 = min(y0 + 1, 27);
  bool hx = (x1 != x0), hy = (y1 != y0);
  int k00 = y0 * 28 + x0, k01 = y0 * 28 + x1, k10 = y1 * 28 + x0, k11 = y1 * 28 + x1;
  const float* Mr = Mmat + (size_t)n * Kk;
  float m00 = Mr[k00];
  float m01 = hx ? Mr[k01] : 0.f;
  float m10 = hy ? Mr[k10] : 0.f;
  float m11 = (hx && hy) ? Mr[k11] : 0.f;
  const float* gb = g + (size_t)b * Kk * Dd;
  int lane = threadIdx.x;
  int l2 = lane + 64;
  float a0 = m00 * gb[k00 * Dd + lane] + m01 * gb[k01 * Dd + lane] +
             m10 * gb[k10 * Dd + lane] + m11 * gb[k11 * Dd + lane];
  float a1 = m00 * gb[k00 * Dd + l2] + m01 * gb[k01 * Dd + l2] +
             m10 * gb[k10 * Dd + l2] + m11 * gb[k11 * Dd + l2];
  float ss = a0 * a0 + a1 * a1;
  for (int off = 32; off; off >>= 1) ss += __shfl_xor(ss, off);
  float inv = 1.0f / fmaxf(sqrtf(ss), 1e-6f);
  E[(size_t)row * Dd + lane] = a0 * inv;
  E[(size_t)row * Dd + l2] = a1 * inv;
}

// ---------------- K7: Saff = (E E^T) * G, symmetric: lower-tri tiles + mirror
__global__ __launch_bounds__(256) void k_saff(
    const float* __restrict__ E, const float* __restrict__ P, float* __restrict__ S) {
  int blk = blockIdx.x;
  int b = blk / 1225;
  int rem = blk % 1225;
  int ti0 = (int)((sqrtf(8.f * rem + 1.f) - 1.f) * 0.5f);
  while ((ti0 + 1) * (ti0 + 2) / 2 <= rem) ++ti0;
  while (ti0 * (ti0 + 1) / 2 > rem) --ti0;
  int tj0 = rem - ti0 * (ti0 + 1) / 2;   // tj0 <= ti0
  int i0 = ti0 * 64, j0 = tj0 * 64;
  __shared__ __align__(16) float Ei_s[64 * 68];
  __shared__ __align__(16) float Ej_s[64 * 68];
  __shared__ float s_pxi[64], s_pyi[64], s_pxj[64], s_pyj[64];
  int tid = threadIdx.x;
  const float* Eb = E + (size_t)b * Nn * Dd;
  if (tid < 64) {
    s_pxi[tid] = P[(i0 + tid) * 2];
    s_pyi[tid] = P[(i0 + tid) * 2 + 1];
    s_pxj[tid] = P[(j0 + tid) * 2];
    s_pyj[tid] = P[(j0 + tid) * 2 + 1];
  }
  int ti = tid >> 4, tj = tid & 15;
  int ib = ti * 4, jb = tj * 4;
  float acc[4][4];
#pragma unroll
  for (int a = 0; a < 4; ++a)
#pragma unroll
    for (int c = 0; c < 4; ++c) acc[a][c] = 0.f;
  for (int kc = 0; kc < Dd; kc += 64) {
    __syncthreads();
    for (int idx = tid; idx < 64 * 64; idx += 256) {
      int ii = idx >> 6, dd = idx & 63;
      Ei_s[dd * 68 + ii] = Eb[(size_t)(i0 + ii) * Dd + kc + dd];
      Ej_s[dd * 68 + ii] = Eb[(size_t)(j0 + ii) * Dd + kc + dd];
    }
    __syncthreads();
#pragma unroll 8
    for (int kk = 0; kk < 64; ++kk) {
      const float4 a = *reinterpret_cast<const float4*>(&Ei_s[kk * 68 + ib]);
      const float4 q = *reinterpret_cast<const float4*>(&Ej_s[kk * 68 + jb]);
      acc[0][0] += a.x * q.x; acc[0][1] += a.x * q.y; acc[0][2] += a.x * q.z; acc[0][3] += a.x * q.w;
      acc[1][0] += a.y * q.x; acc[1][1] += a.y * q.y; acc[1][2] += a.y * q.z; acc[1][3] += a.y * q.w;
      acc[2][0] += a.z * q.x; acc[2][1] += a.z * q.y; acc[2][2] += a.z * q.z; acc[2][3] += a.z * q.w;
      acc[3][0] += a.w * q.x; acc[3][1] += a.w * q.y; acc[3][2] += a.w * q.z; acc[3][3] += a.w * q.w;
    }
  }
  float outv[4][4];
#pragma unroll
  for (int di = 0; di < 4; ++di) {
    float px = s_pxi[ib + di], py = s_pyi[ib + di];
#pragma unroll
    for (int dj = 0; dj < 4; ++dj) {
      float dx = px - s_pxj[jb + dj];
      float dy = py - s_pyj[jb + dj];
      float gg = 1.0f - expf(-(dx * dx + dy * dy) * (1.0f / 18.0f));
      outv[di][dj] = acc[di][dj] * gg;
    }
  }
  size_t ob = (size_t)b * Nn * Nn;
#pragma unroll
  for (int di = 0; di < 4; ++di) {
    float4 o = {outv[di][0], outv[di][1], outv[di][2], outv[di][3]};
    *reinterpret_cast<float4*>(&S[ob + (size_t)(i0 + ib + di) * Nn + j0 + jb]) = o;
  }
  if (i0 != j0) {
#pragma unroll
    for (int dj = 0; dj < 4; ++dj) {
      float4 o = {outv[0][dj], outv[1][dj], outv[2][dj], outv[3][dj]};
      *reinterpret_cast<float4*>(&S[ob + (size_t)(j0 + jb + dj) * Nn + i0 + ib]) = o;
    }
  }
}

// ---------------- K8: exact top-32 per row via 4-pass radix select -----------
__global__ __launch_bounds__(256) void k_topk(
    const float* __restrict__ S, float* __restrict__ topv, int* __restrict__ topi,
    float* __restrict__ dr, float* __restrict__ dc) {
  int row = blockIdx.x;
  int b = row / Nn;
  int tid = threadIdx.x;
  const float* Sr = S + (size_t)row * Nn;
  __shared__ unsigned hist[256 * 8];
  __shared__ unsigned scan_s[256];
  __shared__ unsigned bcast[2];
  __shared__ unsigned sel_eq, sel_slot;
  __shared__ float drow_s;
  unsigned key[13];
#pragma unroll
  for (int j = 0; j < 13; ++j) {
    int c = tid + 256 * j;
    unsigned u = (c < Nn) ? __float_as_uint(Sr[c]) : 0xFF800000u;
    key[j] = u ^ (((unsigned)((int)u >> 31)) | 0x80000000u);
  }
  if (tid == 0) { sel_eq = 0; sel_slot = 0; drow_s = 0.f; }
  unsigned prefix = 0;
  unsigned k = NTOP;
  for (int pass = 0; pass < 4; ++pass) {
    int shift = 24 - 8 * pass;
#pragma unroll
    for (int i = 0; i < 8; ++i) hist[tid * 8 + i] = 0;
    __syncthreads();
    unsigned pmask = pass ? (0xFFFFFFFFu << (shift + 8)) : 0u;
#pragma unroll
    for (int j = 0; j < 13; ++j) {
      if ((key[j] & pmask) == prefix)
        atomicAdd(&hist[((key[j] >> shift) & 255u) * 8 + (tid & 7)], 1u);
    }
    __syncthreads();
    unsigned cnt = 0;
#pragma unroll
    for (int i = 0; i < 8; ++i) cnt += hist[tid * 8 + i];
    unsigned run = cnt;
    scan_s[tid] = run;
    for (int st = 1; st < 256; st <<= 1) {
      __syncthreads();
      unsigned add = (tid + st < 256) ? scan_s[tid + st] : 0u;
      __syncthreads();
      run += add;
      scan_s[tid] = run;
    }
    unsigned incl = run;
    unsigned excl = incl - cnt;
    if (excl < k && k <= incl) {
      bcast[0] = prefix | ((unsigned)tid << shift);
      bcast[1] = k - excl;
    }
    __syncthreads();
    prefix = bcast[0];
    k = bcast[1];
    __syncthreads();
  }
  unsigned T = prefix;
  float esum = 0.f;
#pragma unroll
  for (int j = 0; j < 13; ++j) {
    int c = tid + 256 * j;
    if (c >= Nn) break;
    unsigned kj = key[j];
    bool take = kj > T;
    if (!take && kj == T) take = (atomicAdd(&sel_eq, 1u) < k);
    if (take) {
      unsigned slot = atomicAdd(&sel_slot, 1u);
      float v = __uint_as_float((kj & 0x80000000u) ? (kj ^ 0x80000000u) : ~kj);
      float e = __expf(10.f * v);
      topv[(size_t)row * NTOP + slot] = v;
      topi[(size_t)row * NTOP + slot] = c;
      atomicAdd(&dc[b * Nn + c], e - 1.f);
      esum += e;
    }
  }
  for (int off = 32; off; off >>= 1) esum += __shfl_xor(esum, off);
  if ((tid & 63) == 0) atomicAdd(&drow_s, esum);
  __syncthreads();
  if (tid == 0) dr[row] = (float)(Nn - NTOP) + drow_s;
}

__global__ void k_dcinit(float* __restrict__ dc) {
  int i = blockIdx.x * 256 + threadIdx.x;
  if (i < Bb * Nn) dc[i] = (float)Nn;
}

__global__ void k_inv(float* __restrict__ dr, float* __restrict__ dc) {
  int i = blockIdx.x * 256 + threadIdx.x;
  if (i < Bb * Nn) {
    dr[i] = 1.0f / dr[i];
    dc[i] = 1.0f / dc[i];
  }
}

// ---------------- K10: A0 row = invdr_i * invdc_j, then fix 32 entries -------
__global__ __launch_bounds__(256) void k_basefix(
    const float* __restrict__ invdr, const float* __restrict__ invdc,
    const float* __restrict__ topv, const int* __restrict__ topi,
    float* __restrict__ A0) {
  int row = blockIdx.x;            // b*N + i
  int b = row / Nn;
  float idr = invdr[row];
  const float4* dc4 = reinterpret_cast<const float4*>(invdc + b * Nn);
  float4* out4 = reinterpret_cast<float4*>(A0 + (size_t)row * Nn);
  for (int j = threadIdx.x; j < Nn / 4; j += 256) {
    float4 c = dc4[j];
    float4 o = {idr * c.x, idr * c.y, idr * c.z, idr * c.w};
    out4[j] = o;
  }
  __syncthreads();
  if (threadIdx.x < NTOP) {
    int gidx = row * NTOP + threadIdx.x;
    int col = topi[gidx];
    float e = __expf(10.f * topv[gidx]);
    A0[(size_t)row * Nn + col] = e * e * idr * invdc[b * Nn + col];
  }
}

extern "C" void kernel_launch(void* const* d_in, const int* in_sizes, int n_in,
                              void* d_out, int out_size, void* d_ws, size_t ws_size,
                              hipStream_t stream) {
  const float* fm     = (const float*)d_in[0];
  const float* Abank  = (const float*)d_in[1];
  const float* pw_w   = (const float*)d_in[2];
  const float* pw_b   = (const float*)d_in[3];
  const float* proj_w = (const float*)d_in[4];
  const float* proj_b = (const float*)d_in[5];
  const float* r      = (const float*)d_in[6];
  const float* Mmat   = (const float*)d_in[7];
  const float* P      = (const float*)d_in[8];
  float* out = (float*)d_out;
  float* E  = out;
  float* A0 = out + (size_t)Bb * Nn * Dd;

  float* ws = (float*)d_ws;
  float* y     = ws;                       //  1,605,632 floats (B*D*N)
  float* z     = ws + 1605632;             //  6,422,528 (T*B*K*D)
  float* wct   = ws + 8028160;             //     32,768
  float* bcv   = ws + 8060928;             //        128
  float* s_arr = ws + 8061056;             //     50,176
  float* g     = ws + 8111232;             //    401,408
  float* topv  = ws + 8512640;             //    401,408
  int*   topi  = (int*)(ws + 8914048);     //    401,408
  float* dr    = ws + 9315456;             //     12,544
  float* dc    = ws + 9328000;             //     12,544

  hipLaunchKernelGGL(k_wc, dim3(Cc), dim3(128), 0, stream, pw_w, pw_b, proj_w, proj_b, wct, bcv);
  hipLaunchKernelGGL(k_mix, dim3(448), dim3(256), 0, stream, fm, wct, y);
  hipLaunchKernelGGL(k_fused_pool, dim3(2048), dim3(256), 0, stream, y, Abank, bcv, z);
  hipLaunchKernelGGL(k_znorm, dim3(Tt * Bb * Kk / 4), dim3(256), 0, stream, z, r, s_arr);
  hipLaunchKernelGGL(k_gemb, dim3(Bb * Kk), dim3(128), 0, stream, z, s_arr, g);
  hipLaunchKernelGGL(k_E, dim3(Bb * Nn), dim3(64), 0, stream, Mmat, g, E);
  hipLaunchKernelGGL(k_saff, dim3(Bb * 1225), dim3(256), 0, stream, E, P, A0);
  hipLaunchKernelGGL(k_dcinit, dim3(49), dim3(256), 0, stream, dc);
  hipLaunchKernelGGL(k_topk, dim3(Bb * Nn), dim3(256), 0, stream, A0, topv, topi, dr, dc);
  hipLaunchKernelGGL(k_inv, dim3(49), dim3(256), 0, stream, dr, dc);
  hipLaunchKernelGGL(k_basefix, dim3(Bb * Nn), dim3(256), 0, stream, dr, dc, topv, topi, A0);
}

// Round 2
// 521.571 us; speedup vs baseline: 1.3371x; 1.0197x over previous
//
#include <hip/hip_runtime.h>
#include <hip/hip_bf16.h>

#define Hh 56
#define Ww 56
#define Cc 256
#define Tt 16
#define Bb 4
#define Nn 3136
#define Kk 784
#define KX 28
#define Dd 128
#define Mc 64
#define NTOP 32

// ---------------- K3a: combined weight Wc^T [c][d] and bias bc ---------------
__global__ __launch_bounds__(128) void k_wc(
    const float* __restrict__ pw_w, const float* __restrict__ pw_b,
    const float* __restrict__ proj_w, const float* __restrict__ proj_b,
    float* __restrict__ wct, float* __restrict__ bc) {
  int c = blockIdx.x;
  int d = threadIdx.x;
  float acc = 0.f;
  for (int m = 0; m < Mc; ++m) acc += proj_w[d * Mc + m] * pw_w[m * Cc + c];
  wct[c * Dd + d] = acc;
  if (c == 0) {
    float bb = proj_b[d];
    for (int m = 0; m < Mc; ++m) bb += proj_w[d * Mc + m] * pw_b[m];
    bc[d] = bb;
  }
}

// ---- K_mix: y[b][d][n] = sum_c fm[b][c][n] * wct[c][d]  (channel mix FIRST;
//      commutes with warp+pool since those are per-channel spatial linear ops)
// grid: b(4) x ntile(112 of 28) = 448 blocks, 256 thr
__global__ __launch_bounds__(256) void k_mix(
    const float* __restrict__ fm, const float* __restrict__ wct, float* __restrict__ y) {
  int blk = blockIdx.x;
  int b = blk / 112;
  int n0 = (blk % 112) * 28;
  int tid = threadIdx.x;
  int d = tid & 127;
  int ng = tid >> 7;               // 0..1
  __shared__ float fm_s[64 * 28];
  __shared__ float wc_s[64 * Dd];
  float acc[14];
#pragma unroll
  for (int j = 0; j < 14; ++j) acc[j] = 0.f;
  const float* fb = fm + (size_t)b * Cc * Nn;
  for (int c0 = 0; c0 < Cc; c0 += 64) {
    for (int i = tid; i < 64 * 28; i += 256) {
      int c = i / 28, kx = i - c * 28;
      fm_s[i] = fb[(size_t)(c0 + c) * Nn + n0 + kx];
    }
    for (int i = tid; i < 64 * Dd; i += 256) wc_s[i] = wct[c0 * Dd + i];
    __syncthreads();
    for (int c = 0; c < 64; ++c) {
      float w = wc_s[c * Dd + d];
#pragma unroll
      for (int j = 0; j < 14; ++j) acc[j] += fm_s[c * 28 + ng * 14 + j] * w;
    }
    __syncthreads();
  }
  float* yo = y + ((size_t)b * Dd + d) * Nn + n0 + ng * 14;
#pragma unroll
  for (int j = 0; j < 14; ++j) yo[j] = acc[j];
}

// ---- K1: fused affine warp + bilinear + 9x9/s2 zero-pad avg-pool on mixed y
//      writes zt[((t*B+b)*D + d)*K + k] = pooled + bc[d]   (d-major, k-contig
//      -> fully coalesced stores; transpose to [k][d] is folded into k_znorm)
// grid: b(4) x dg(32 of 4 d) x t(16) = 2048 blocks, 256 thr
__global__ __launch_bounds__(256) void k_fused_pool(
    const float* __restrict__ y, const float* __restrict__ Abank,
    const float* __restrict__ bc, float* __restrict__ zt) {
  int idx = blockIdx.x;
  int b = idx & 3;
  int dg = (idx >> 2) & 31;
  int t = idx >> 7;
  __shared__ float wsm[3136];
  __shared__ float rowp[1568];
  int tid = threadIdx.x;
  const float* A = Abank + t * 6;
  float a00 = A[0], a01 = A[1], a02 = A[2], a10 = A[3], a11 = A[4], a12 = A[5];
  // per-thread coords for its ~13 pixels (t-dependent only, reused for 4 d)
  int off[13];
  float wxa[13], wya[13];
#pragma unroll
  for (int j = 0; j < 13; ++j) {
    int e = tid + 256 * j;
    if (e < 3136) {
      int h = e / 56, w = e - h * 56;
      float gx = (2.0f * w + 1.0f) / 56.0f - 1.0f;
      float gy = (2.0f * h + 1.0f) / 56.0f - 1.0f;
      float u = a00 * gx + a01 * gy + a02;
      float v = a10 * gx + a11 * gy + a12;
      float ix = ((u + 1.0f) * 56.0f - 1.0f) * 0.5f;
      float iy = ((v + 1.0f) * 56.0f - 1.0f) * 0.5f;
      float x0f = floorf(ix), y0f = floorf(iy);
      wxa[j] = ix - x0f;
      wya[j] = iy - y0f;
      int x0 = (int)x0f, y0 = (int)y0f;
      int x0c = min(max(x0, 0), 55), x1c = min(max(x0 + 1, 0), 55);
      int y0c = min(max(y0, 0), 55), y1c = min(max(y0 + 1, 0), 55);
      off[j] = (y0c * 56 + x0c) | ((x1c - x0c) << 12) | ((y1c - y0c) << 13);
    }
  }
  for (int dd = 0; dd < 4; ++dd) {
    int d = dg * 4 + dd;
    const float* fc = y + ((size_t)b * Dd + d) * Nn;
    float bias = bc[d];
    // stage A: warped -> wsm (taps from global, cache-served)
#pragma unroll
    for (int j = 0; j < 13; ++j) {
      int e = tid + 256 * j;
      if (e < 3136) {
        int pk = off[j];
        int base = pk & 4095;
        int dx = (pk >> 12) & 1;
        int dyy = (pk & (1 << 13)) ? 56 : 0;
        float v00 = fc[base], v01 = fc[base + dx];
        float v10 = fc[base + dyy], v11 = fc[base + dyy + dx];
        float wx = wxa[j], wy = wya[j];
        float top = v00 + wx * (v01 - v00);
        float bot = v10 + wx * (v11 - v10);
        wsm[e] = top + wy * (bot - top);
      }
    }
    __syncthreads();
    // stage B: row pool (horizontal 9, stride 2) -> rowp[56][28]
    for (int e = tid; e < 1568; e += 256) {
      int h = e / 28, kx = e - h * 28;
      int xs = 2 * kx - 4;
      int lo = max(xs, 0), hi = min(xs + 8, 55);
      float s = 0.f;
      const float* wr = wsm + h * 56;
      for (int x = lo; x <= hi; ++x) s += wr[x];
      rowp[e] = s;
    }
    __syncthreads();
    // stage C: col pool (vertical 9, stride 2) -> zt (+bias), k-contig stores
    float* zo = zt + ((size_t)(t * Bb + b) * Dd + d) * Kk;
    for (int e = tid; e < 784; e += 256) {
      int ky = e / 28, kx = e - ky * 28;
      int ys = 2 * ky - 4;
      int lo = max(ys, 0), hi = min(ys + 8, 55);
      float s = 0.f;
      for (int h = lo; h <= hi; ++h) s += rowp[h * 28 + kx];
      zo[e] = s * (1.0f / 81.0f) + bias;
    }
    __syncthreads();
  }
}

// ---- K4: transpose zt -> z (normalized, [tb][k][d]) + s = zn . r ------------
// grid: tb(64) x ktile(14 of 56) = 896 blocks, 256 thr
// Loads [128d x 56k] coalesced from zt, LDS-transpose (pitch 129, conflict-
// free), shuffle-reduce norm per k, writes z rows coalesced (512B per k).
__global__ __launch_bounds__(256) void k_znorm(
    const float* __restrict__ zt, const float* __restrict__ r,
    float* __restrict__ z, float* __restrict__ s_arr) {
  int tb = blockIdx.x / 14;
  int k0 = (blockIdx.x % 14) * 56;
  int tid = threadIdx.x;
  __shared__ float ls[56 * 129];
  const float* zb = zt + (size_t)tb * Dd * Kk + k0;
  for (int i = tid; i < Dd * 56; i += 256) {
    int d = i / 56, kk = i - d * 56;
    ls[kk * 129 + d] = zb[(size_t)d * Kk + kk];
  }
  int lane = tid & 63;
  int wv = tid >> 6;               // 0..3
  float r0 = r[lane], r1 = r[lane + 64];
  __syncthreads();
  for (int p = 0; p < 14; ++p) {
    int k = p * 4 + wv;
    float z0 = ls[k * 129 + lane];
    float z1 = ls[k * 129 + 64 + lane];
    float ss = z0 * z0 + z1 * z1;
    for (int off = 32; off; off >>= 1) ss += __shfl_xor(ss, off);
    float inv = 1.0f / fmaxf(sqrtf(ss), 1e-6f);
    z0 *= inv; z1 *= inv;
    float* zr = z + ((size_t)tb * Kk + k0 + k) * Dd;
    zr[lane] = z0;
    zr[lane + 64] = z1;
    float sd = z0 * r0 + z1 * r1;
    for (int off = 32; off; off >>= 1) sd += __shfl_xor(sd, off);
    if (lane == 0) s_arr[(size_t)tb * Kk + k0 + k] = sd;
  }
}

// ---------------- K5: softmax over T, g_emb ----------------------------------
__global__ __launch_bounds__(128) void k_gemb(
    const float* __restrict__ z, const float* __restrict__ s_arr, float* __restrict__ g) {
  int blk = blockIdx.x;            // b*784 + k
  int b = blk / Kk, k = blk % Kk;
  int d = threadIdx.x;
  float sv[Tt];
  float mx = -3.4e38f;
#pragma unroll
  for (int t = 0; t < Tt; ++t) {
    sv[t] = s_arr[(t * Bb + b) * Kk + k];
    mx = fmaxf(mx, sv[t]);
  }
  float sum = 0.f;
#pragma unroll
  for (int t = 0; t < Tt; ++t) {
    sv[t] = expf(10.0f * (sv[t] - mx));
    sum += sv[t];
  }
  float isum = 1.0f / sum;
  float acc = 0.f;
#pragma unroll
  for (int t = 0; t < Tt; ++t)
    acc += sv[t] * isum * z[((size_t)(t * Bb + b) * Kk + k) * Dd + d];
  g[((size_t)b * Kk + k) * Dd + d] = acc;
}

// ---------------- K6: E = normalize(M @ g) via sparse bilinear structure -----
__global__ __launch_bounds__(64) void k_E(
    const float* __restrict__ Mmat, const float* __restrict__ g, float* __restrict__ E) {
  int row = blockIdx.x;            // b*N + n
  int b = row / Nn, n = row % Nn;
  int y = n / Ww, x = n % Ww;
  int x0 = x >> 1, y0 = y >> 1;
  int x1 = min(x0 + 1, 27), y1 = min(y0 + 1, 27);
  bool hx = (x1 != x0), hy = (y1 != y0);
  int k00 = y0 * 28 + x0, k01 = y0 * 28 + x1, k10 = y1 * 28 + x0, k11 = y1 * 28 + x1;
  const float* Mr = Mmat + (size_t)n * Kk;
  float m00 = Mr[k00];
  float m01 = hx ? Mr[k01] : 0.f;
  float m10 = hy ? Mr[k10] : 0.f;
  float m11 = (hx && hy) ? Mr[k11] : 0.f;
  const float* gb = g + (size_t)b * Kk * Dd;
  int lane = threadIdx.x;
  int l2 = lane + 64;
  float a0 = m00 * gb[k00 * Dd + lane] + m01 * gb[k01 * Dd + lane] +
             m10 * gb[k10 * Dd + lane] + m11 * gb[k11 * Dd + lane];
  float a1 = m00 * gb[k00 * Dd + l2] + m01 * gb[k01 * Dd + l2] +
             m10 * gb[k10 * Dd + l2] + m11 * gb[k11 * Dd + l2];
  float ss = a0 * a0 + a1 * a1;
  for (int off = 32; off; off >>= 1) ss += __shfl_xor(ss, off);
  float inv = 1.0f / fmaxf(sqrtf(ss), 1e-6f);
  E[(size_t)row * Dd + lane] = a0 * inv;
  E[(size_t)row * Dd + l2] = a1 * inv;
}

// ---------------- K7: Saff = (E E^T) * G, symmetric: lower-tri tiles + mirror
__global__ __launch_bounds__(256) void k_saff(
    const float* __restrict__ E, const float* __restrict__ P, float* __restrict__ S) {
  int blk = blockIdx.x;
  int b = blk / 1225;
  int rem = blk % 1225;
  int ti0 = (int)((sqrtf(8.f * rem + 1.f) - 1.f) * 0.5f);
  while ((ti0 + 1) * (ti0 + 2) / 2 <= rem) ++ti0;
  while (ti0 * (ti0 + 1) / 2 > rem) --ti0;
  int tj0 = rem - ti0 * (ti0 + 1) / 2;   // tj0 <= ti0
  int i0 = ti0 * 64, j0 = tj0 * 64;
  __shared__ __align__(16) float Ei_s[64 * 68];
  __shared__ __align__(16) float Ej_s[64 * 68];
  __shared__ float s_pxi[64], s_pyi[64], s_pxj[64], s_pyj[64];
  int tid = threadIdx.x;
  const float* Eb = E + (size_t)b * Nn * Dd;
  if (tid < 64) {
    s_pxi[tid] = P[(i0 + tid) * 2];
    s_pyi[tid] = P[(i0 + tid) * 2 + 1];
    s_pxj[tid] = P[(j0 + tid) * 2];
    s_pyj[tid] = P[(j0 + tid) * 2 + 1];
  }
  int ti = tid >> 4, tj = tid & 15;
  int ib = ti * 4, jb = tj * 4;
  float acc[4][4];
#pragma unroll
  for (int a = 0; a < 4; ++a)
#pragma unroll
    for (int c = 0; c < 4; ++c) acc[a][c] = 0.f;
  for (int kc = 0; kc < Dd; kc += 64) {
    __syncthreads();
    for (int idx = tid; idx < 64 * 64; idx += 256) {
      int ii = idx >> 6, dd = idx & 63;
      Ei_s[dd * 68 + ii] = Eb[(size_t)(i0 + ii) * Dd + kc + dd];
      Ej_s[dd * 68 + ii] = Eb[(size_t)(j0 + ii) * Dd + kc + dd];
    }
    __syncthreads();
#pragma unroll 8
    for (int kk = 0; kk < 64; ++kk) {
      const float4 a = *reinterpret_cast<const float4*>(&Ei_s[kk * 68 + ib]);
      const float4 q = *reinterpret_cast<const float4*>(&Ej_s[kk * 68 + jb]);
      acc[0][0] += a.x * q.x; acc[0][1] += a.x * q.y; acc[0][2] += a.x * q.z; acc[0][3] += a.x * q.w;
      acc[1][0] += a.y * q.x; acc[1][1] += a.y * q.y; acc[1][2] += a.y * q.z; acc[1][3] += a.y * q.w;
      acc[2][0] += a.z * q.x; acc[2][1] += a.z * q.y; acc[2][2] += a.z * q.z; acc[2][3] += a.z * q.w;
      acc[3][0] += a.w * q.x; acc[3][1] += a.w * q.y; acc[3][2] += a.w * q.z; acc[3][3] += a.w * q.w;
    }
  }
  float outv[4][4];
#pragma unroll
  for (int di = 0; di < 4; ++di) {
    float px = s_pxi[ib + di], py = s_pyi[ib + di];
#pragma unroll
    for (int dj = 0; dj < 4; ++dj) {
      float dx = px - s_pxj[jb + dj];
      float dy = py - s_pyj[jb + dj];
      float gg = 1.0f - expf(-(dx * dx + dy * dy) * (1.0f / 18.0f));
      outv[di][dj] = acc[di][dj] * gg;
    }
  }
  size_t ob = (size_t)b * Nn * Nn;
#pragma unroll
  for (int di = 0; di < 4; ++di) {
    float4 o = {outv[di][0], outv[di][1], outv[di][2], outv[di][3]};
    *reinterpret_cast<float4*>(&S[ob + (size_t)(i0 + ib + di) * Nn + j0 + jb]) = o;
  }
  if (i0 != j0) {
#pragma unroll
    for (int dj = 0; dj < 4; ++dj) {
      float4 o = {outv[0][dj], outv[1][dj], outv[2][dj], outv[3][dj]};
      *reinterpret_cast<float4*>(&S[ob + (size_t)(j0 + jb + dj) * Nn + i0 + ib]) = o;
    }
  }
}

// ---------------- K8: exact top-32 per row via 4-pass radix select -----------
__global__ __launch_bounds__(256) void k_topk(
    const float* __restrict__ S, float* __restrict__ topv, int* __restrict__ topi,
    float* __restrict__ dr, float* __restrict__ dc) {
  int row = blockIdx.x;
  int b = row / Nn;
  int tid = threadIdx.x;
  const float* Sr = S + (size_t)row * Nn;
  __shared__ unsigned hist[256 * 8];
  __shared__ unsigned scan_s[256];
  __shared__ unsigned bcast[2];
  __shared__ unsigned sel_eq, sel_slot;
  __shared__ float drow_s;
  unsigned key[13];
#pragma unroll
  for (int j = 0; j < 13; ++j) {
    int c = tid + 256 * j;
    unsigned u = (c < Nn) ? __float_as_uint(Sr[c]) : 0xFF800000u;
    key[j] = u ^ (((unsigned)((int)u >> 31)) | 0x80000000u);
  }
  if (tid == 0) { sel_eq = 0; sel_slot = 0; drow_s = 0.f; }
  unsigned prefix = 0;
  unsigned k = NTOP;
  for (int pass = 0; pass < 4; ++pass) {
    int shift = 24 - 8 * pass;
#pragma unroll
    for (int i = 0; i < 8; ++i) hist[tid * 8 + i] = 0;
    __syncthreads();
    unsigned pmask = pass ? (0xFFFFFFFFu << (shift + 8)) : 0u;
#pragma unroll
    for (int j = 0; j < 13; ++j) {
      if ((key[j] & pmask) == prefix)
        atomicAdd(&hist[((key[j] >> shift) & 255u) * 8 + (tid & 7)], 1u);
    }
    __syncthreads();
    unsigned cnt = 0;
#pragma unroll
    for (int i = 0; i < 8; ++i) cnt += hist[tid * 8 + i];
    unsigned run = cnt;
    scan_s[tid] = run;
    for (int st = 1; st < 256; st <<= 1) {
      __syncthreads();
      unsigned add = (tid + st < 256) ? scan_s[tid + st] : 0u;
      __syncthreads();
      run += add;
      scan_s[tid] = run;
    }
    unsigned incl = run;
    unsigned excl = incl - cnt;
    if (excl < k && k <= incl) {
      bcast[0] = prefix | ((unsigned)tid << shift);
      bcast[1] = k - excl;
    }
    __syncthreads();
    prefix = bcast[0];
    k = bcast[1];
    __syncthreads();
  }
  unsigned T = prefix;
  float esum = 0.f;
#pragma unroll
  for (int j = 0; j < 13; ++j) {
    int c = tid + 256 * j;
    if (c >= Nn) break;
    unsigned kj = key[j];
    bool take = kj > T;
    if (!take && kj == T) take = (atomicAdd(&sel_eq, 1u) < k);
    if (take) {
      unsigned slot = atomicAdd(&sel_slot, 1u);
      float v = __uint_as_float((kj & 0x80000000u) ? (kj ^ 0x80000000u) : ~kj);
      float e = __expf(10.f * v);
      topv[(size_t)row * NTOP + slot] = v;
      topi[(size_t)row * NTOP + slot] = c;
      atomicAdd(&dc[b * Nn + c], e - 1.f);
      esum += e;
    }
  }
  for (int off = 32; off; off >>= 1) esum += __shfl_xor(esum, off);
  if ((tid & 63) == 0) atomicAdd(&drow_s, esum);
  __syncthreads();
  if (tid == 0) dr[row] = (float)(Nn - NTOP) + drow_s;
}

__global__ void k_dcinit(float* __restrict__ dc) {
  int i = blockIdx.x * 256 + threadIdx.x;
  if (i < Bb * Nn) dc[i] = (float)Nn;
}

__global__ void k_inv(float* __restrict__ dr, float* __restrict__ dc) {
  int i = blockIdx.x * 256 + threadIdx.x;
  if (i < Bb * Nn) {
    dr[i] = 1.0f / dr[i];
    dc[i] = 1.0f / dc[i];
  }
}

// ---------------- K10: A0 row = invdr_i * invdc_j, then fix 32 entries -------
__global__ __launch_bounds__(256) void k_basefix(
    const float* __restrict__ invdr, const float* __restrict__ invdc,
    const float* __restrict__ topv, const int* __restrict__ topi,
    float* __restrict__ A0) {
  int row = blockIdx.x;            // b*N + i
  int b = row / Nn;
  float idr = invdr[row];
  const float4* dc4 = reinterpret_cast<const float4*>(invdc + b * Nn);
  float4* out4 = reinterpret_cast<float4*>(A0 + (size_t)row * Nn);
  for (int j = threadIdx.x; j < Nn / 4; j += 256) {
    float4 c = dc4[j];
    float4 o = {idr * c.x, idr * c.y, idr * c.z, idr * c.w};
    out4[j] = o;
  }
  __syncthreads();
  if (threadIdx.x < NTOP) {
    int gidx = row * NTOP + threadIdx.x;
    int col = topi[gidx];
    float e = __expf(10.f * topv[gidx]);
    A0[(size_t)row * Nn + col] = e * e * idr * invdc[b * Nn + col];
  }
}

extern "C" void kernel_launch(void* const* d_in, const int* in_sizes, int n_in,
                              void* d_out, int out_size, void* d_ws, size_t ws_size,
                              hipStream_t stream) {
  const float* fm     = (const float*)d_in[0];
  const float* Abank  = (const float*)d_in[1];
  const float* pw_w   = (const float*)d_in[2];
  const float* pw_b   = (const float*)d_in[3];
  const float* proj_w = (const float*)d_in[4];
  const float* proj_b = (const float*)d_in[5];
  const float* r      = (const float*)d_in[6];
  const float* Mmat   = (const float*)d_in[7];
  const float* P      = (const float*)d_in[8];
  float* out = (float*)d_out;
  float* E  = out;
  float* A0 = out + (size_t)Bb * Nn * Dd;

  float* ws = (float*)d_ws;
  float* y     = ws;                       //  1,605,632 floats (B*D*N)
  float* zt    = ws + 1605632;             //  6,422,528 (T*B*D*K, d-major)
  float* z     = ws + 8028160;             //  6,422,528 (T*B*K*D, normalized)
  float* wct   = ws + 14450688;            //     32,768
  float* bcv   = ws + 14483456;            //        128
  float* s_arr = ws + 14483584;            //     50,176
  float* g     = ws + 14533760;            //    401,408
  float* topv  = ws + 14935168;            //    401,408
  int*   topi  = (int*)(ws + 15336576);    //    401,408
  float* dr    = ws + 15737984;            //     12,544
  float* dc    = ws + 15750528;            //     12,544

  hipLaunchKernelGGL(k_wc, dim3(Cc), dim3(128), 0, stream, pw_w, pw_b, proj_w, proj_b, wct, bcv);
  hipLaunchKernelGGL(k_mix, dim3(448), dim3(256), 0, stream, fm, wct, y);
  hipLaunchKernelGGL(k_fused_pool, dim3(2048), dim3(256), 0, stream, y, Abank, bcv, zt);
  hipLaunchKernelGGL(k_znorm, dim3(64 * 14), dim3(256), 0, stream, zt, r, z, s_arr);
  hipLaunchKernelGGL(k_gemb, dim3(Bb * Kk), dim3(128), 0, stream, z, s_arr, g);
  hipLaunchKernelGGL(k_E, dim3(Bb * Nn), dim3(64), 0, stream, Mmat, g, E);
  hipLaunchKernelGGL(k_saff, dim3(Bb * 1225), dim3(256), 0, stream, E, P, A0);
  hipLaunchKernelGGL(k_dcinit, dim3(49), dim3(256), 0, stream, dc);
  hipLaunchKernelGGL(k_topk, dim3(Bb * Nn), dim3(256), 0, stream, A0, topv, topi, dr, dc);
  hipLaunchKernelGGL(k_inv, dim3(49), dim3(256), 0, stream, dr, dc);
  hipLaunchKernelGGL(k_basefix, dim3(Bb * Nn), dim3(256), 0, stream, dr, dc, topv, topi, A0);
}

// Round 3
// 515.826 us; speedup vs baseline: 1.3520x; 1.0111x over previous
//
#include <hip/hip_runtime.h>
#include <hip/hip_bf16.h>
#include <hip/hip_fp16.h>

#define Hh 56
#define Ww 56
#define Cc 256
#define Tt 16
#define Bb 4
#define Nn 3136
#define Kk 784
#define KX 28
#define Dd 128
#define Mc 64
#define NTOP 32

// ---------------- K3a: combined weight Wc^T [c][d] and bias bc ---------------
__global__ __launch_bounds__(128) void k_wc(
    const float* __restrict__ pw_w, const float* __restrict__ pw_b,
    const float* __restrict__ proj_w, const float* __restrict__ proj_b,
    float* __restrict__ wct, float* __restrict__ bc) {
  int c = blockIdx.x;
  int d = threadIdx.x;
  float acc = 0.f;
  for (int m = 0; m < Mc; ++m) acc += proj_w[d * Mc + m] * pw_w[m * Cc + c];
  wct[c * Dd + d] = acc;
  if (c == 0) {
    float bb = proj_b[d];
    for (int m = 0; m < Mc; ++m) bb += proj_w[d * Mc + m] * pw_b[m];
    bc[d] = bb;
  }
}

// ---- K_mix: y[b][d][n] = sum_c fm[b][c][n] * wct[c][d]  (channel mix FIRST;
//      commutes with warp+pool since those are per-channel spatial linear ops)
__global__ __launch_bounds__(256) void k_mix(
    const float* __restrict__ fm, const float* __restrict__ wct, float* __restrict__ y) {
  int blk = blockIdx.x;
  int b = blk / 112;
  int n0 = (blk % 112) * 28;
  int tid = threadIdx.x;
  int d = tid & 127;
  int ng = tid >> 7;               // 0..1
  __shared__ float fm_s[64 * 28];
  __shared__ float wc_s[64 * Dd];
  float acc[14];
#pragma unroll
  for (int j = 0; j < 14; ++j) acc[j] = 0.f;
  const float* fb = fm + (size_t)b * Cc * Nn;
  for (int c0 = 0; c0 < Cc; c0 += 64) {
    for (int i = tid; i < 64 * 28; i += 256) {
      int c = i / 28, kx = i - c * 28;
      fm_s[i] = fb[(size_t)(c0 + c) * Nn + n0 + kx];
    }
    for (int i = tid; i < 64 * Dd; i += 256) wc_s[i] = wct[c0 * Dd + i];
    __syncthreads();
    for (int c = 0; c < 64; ++c) {
      float w = wc_s[c * Dd + d];
#pragma unroll
      for (int j = 0; j < 14; ++j) acc[j] += fm_s[c * 28 + ng * 14 + j] * w;
    }
    __syncthreads();
  }
  float* yo = y + ((size_t)b * Dd + d) * Nn + n0 + ng * 14;
#pragma unroll
  for (int j = 0; j < 14; ++j) yo[j] = acc[j];
}

// ---- K1: fused affine warp + bilinear + 9x9/s2 zero-pad avg-pool on mixed y
//      writes zt[((t*B+b)*D + d)*K + k] = pooled + bc[d]   (d-major, k-contig)
__global__ __launch_bounds__(256) void k_fused_pool(
    const float* __restrict__ y, const float* __restrict__ Abank,
    const float* __restrict__ bc, float* __restrict__ zt) {
  int idx = blockIdx.x;
  int b = idx & 3;
  int dg = (idx >> 2) & 31;
  int t = idx >> 7;
  __shared__ float wsm[3136];
  __shared__ float rowp[1568];
  int tid = threadIdx.x;
  const float* A = Abank + t * 6;
  float a00 = A[0], a01 = A[1], a02 = A[2], a10 = A[3], a11 = A[4], a12 = A[5];
  int off[13];
  float wxa[13], wya[13];
#pragma unroll
  for (int j = 0; j < 13; ++j) {
    int e = tid + 256 * j;
    if (e < 3136) {
      int h = e / 56, w = e - h * 56;
      float gx = (2.0f * w + 1.0f) / 56.0f - 1.0f;
      float gy = (2.0f * h + 1.0f) / 56.0f - 1.0f;
      float u = a00 * gx + a01 * gy + a02;
      float v = a10 * gx + a11 * gy + a12;
      float ix = ((u + 1.0f) * 56.0f - 1.0f) * 0.5f;
      float iy = ((v + 1.0f) * 56.0f - 1.0f) * 0.5f;
      float x0f = floorf(ix), y0f = floorf(iy);
      wxa[j] = ix - x0f;
      wya[j] = iy - y0f;
      int x0 = (int)x0f, y0 = (int)y0f;
      int x0c = min(max(x0, 0), 55), x1c = min(max(x0 + 1, 0), 55);
      int y0c = min(max(y0, 0), 55), y1c = min(max(y0 + 1, 0), 55);
      off[j] = (y0c * 56 + x0c) | ((x1c - x0c) << 12) | ((y1c - y0c) << 13);
    }
  }
  for (int dd = 0; dd < 4; ++dd) {
    int d = dg * 4 + dd;
    const float* fc = y + ((size_t)b * Dd + d) * Nn;
    float bias = bc[d];
#pragma unroll
    for (int j = 0; j < 13; ++j) {
      int e = tid + 256 * j;
      if (e < 3136) {
        int pk = off[j];
        int base = pk & 4095;
        int dx = (pk >> 12) & 1;
        int dyy = (pk & (1 << 13)) ? 56 : 0;
        float v00 = fc[base], v01 = fc[base + dx];
        float v10 = fc[base + dyy], v11 = fc[base + dyy + dx];
        float wx = wxa[j], wy = wya[j];
        float top = v00 + wx * (v01 - v00);
        float bot = v10 + wx * (v11 - v10);
        wsm[e] = top + wy * (bot - top);
      }
    }
    __syncthreads();
    for (int e = tid; e < 1568; e += 256) {
      int h = e / 28, kx = e - h * 28;
      int xs = 2 * kx - 4;
      int lo = max(xs, 0), hi = min(xs + 8, 55);
      float s = 0.f;
      const float* wr = wsm + h * 56;
      for (int x = lo; x <= hi; ++x) s += wr[x];
      rowp[e] = s;
    }
    __syncthreads();
    float* zo = zt + ((size_t)(t * Bb + b) * Dd + d) * Kk;
    for (int e = tid; e < 784; e += 256) {
      int ky = e / 28, kx = e - ky * 28;
      int ys = 2 * ky - 4;
      int lo = max(ys, 0), hi = min(ys + 8, 55);
      float s = 0.f;
      for (int h = lo; h <= hi; ++h) s += rowp[h * 28 + kx];
      zo[e] = s * (1.0f / 81.0f) + bias;
    }
    __syncthreads();
  }
}

// ---- K4: transpose zt -> z (normalized, [tb][k][d]) + s = zn . r ------------
__global__ __launch_bounds__(256) void k_znorm(
    const float* __restrict__ zt, const float* __restrict__ r,
    float* __restrict__ z, float* __restrict__ s_arr) {
  int tb = blockIdx.x / 14;
  int k0 = (blockIdx.x % 14) * 56;
  int tid = threadIdx.x;
  __shared__ float ls[56 * 129];
  const float* zb = zt + (size_t)tb * Dd * Kk + k0;
  for (int i = tid; i < Dd * 56; i += 256) {
    int d = i / 56, kk = i - d * 56;
    ls[kk * 129 + d] = zb[(size_t)d * Kk + kk];
  }
  int lane = tid & 63;
  int wv = tid >> 6;               // 0..3
  float r0 = r[lane], r1 = r[lane + 64];
  __syncthreads();
  for (int p = 0; p < 14; ++p) {
    int k = p * 4 + wv;
    float z0 = ls[k * 129 + lane];
    float z1 = ls[k * 129 + 64 + lane];
    float ss = z0 * z0 + z1 * z1;
    for (int off = 32; off; off >>= 1) ss += __shfl_xor(ss, off);
    float inv = 1.0f / fmaxf(sqrtf(ss), 1e-6f);
    z0 *= inv; z1 *= inv;
    float* zr = z + ((size_t)tb * Kk + k0 + k) * Dd;
    zr[lane] = z0;
    zr[lane + 64] = z1;
    float sd = z0 * r0 + z1 * r1;
    for (int off = 32; off; off >>= 1) sd += __shfl_xor(sd, off);
    if (lane == 0) s_arr[(size_t)tb * Kk + k0 + k] = sd;
  }
}

// ---------------- K5: softmax over T, g_emb ----------------------------------
__global__ __launch_bounds__(128) void k_gemb(
    const float* __restrict__ z, const float* __restrict__ s_arr, float* __restrict__ g) {
  int blk = blockIdx.x;            // b*784 + k
  int b = blk / Kk, k = blk % Kk;
  int d = threadIdx.x;
  float sv[Tt];
  float mx = -3.4e38f;
#pragma unroll
  for (int t = 0; t < Tt; ++t) {
    sv[t] = s_arr[(t * Bb + b) * Kk + k];
    mx = fmaxf(mx, sv[t]);
  }
  float sum = 0.f;
#pragma unroll
  for (int t = 0; t < Tt; ++t) {
    sv[t] = expf(10.0f * (sv[t] - mx));
    sum += sv[t];
  }
  float isum = 1.0f / sum;
  float acc = 0.f;
#pragma unroll
  for (int t = 0; t < Tt; ++t)
    acc += sv[t] * isum * z[((size_t)(t * Bb + b) * Kk + k) * Dd + d];
  g[((size_t)b * Kk + k) * Dd + d] = acc;
}

// ---------------- K6: E = normalize(M @ g) via sparse bilinear structure -----
__global__ __launch_bounds__(64) void k_E(
    const float* __restrict__ Mmat, const float* __restrict__ g, float* __restrict__ E) {
  int row = blockIdx.x;            // b*N + n
  int b = row / Nn, n = row % Nn;
  int y = n / Ww, x = n % Ww;
  int x0 = x >> 1, y0 = y >> 1;
  int x1 = min(x0 + 1, 27), y1 = min(y0 + 1, 27);
  bool hx = (x1 != x0), hy = (y1 != y0);
  int k00 = y0 * 28 + x0, k01 = y0 * 28 + x1, k10 = y1 * 28 + x0, k11 = y1 * 28 + x1;
  const float* Mr = Mmat + (size_t)n * Kk;
  float m00 = Mr[k00];
  float m01 = hx ? Mr[k01] : 0.f;
  float m10 = hy ? Mr[k10] : 0.f;
  float m11 = (hx && hy) ? Mr[k11] : 0.f;
  const float* gb = g + (size_t)b * Kk * Dd;
  int lane = threadIdx.x;
  int l2 = lane + 64;
  float a0 = m00 * gb[k00 * Dd + lane] + m01 * gb[k01 * Dd + lane] +
             m10 * gb[k10 * Dd + lane] + m11 * gb[k11 * Dd + lane];
  float a1 = m00 * gb[k00 * Dd + l2] + m01 * gb[k01 * Dd + l2] +
             m10 * gb[k10 * Dd + l2] + m11 * gb[k11 * Dd + l2];
  float ss = a0 * a0 + a1 * a1;
  for (int off = 32; off; off >>= 1) ss += __shfl_xor(ss, off);
  float inv = 1.0f / fmaxf(sqrtf(ss), 1e-6f);
  E[(size_t)row * Dd + lane] = a0 * inv;
  E[(size_t)row * Dd + l2] = a1 * inv;
}

// ---------------- K7: Saff = (E E^T) * G -> fp16, symmetric tiles + mirror ---
__global__ __launch_bounds__(256) void k_saff(
    const float* __restrict__ E, const float* __restrict__ P, __half* __restrict__ S) {
  int blk = blockIdx.x;
  int b = blk / 1225;
  int rem = blk % 1225;
  int ti0 = (int)((sqrtf(8.f * rem + 1.f) - 1.f) * 0.5f);
  while ((ti0 + 1) * (ti0 + 2) / 2 <= rem) ++ti0;
  while (ti0 * (ti0 + 1) / 2 > rem) --ti0;
  int tj0 = rem - ti0 * (ti0 + 1) / 2;   // tj0 <= ti0
  int i0 = ti0 * 64, j0 = tj0 * 64;
  __shared__ __align__(16) float Ei_s[64 * 68];
  __shared__ __align__(16) float Ej_s[64 * 68];
  __shared__ float s_pxi[64], s_pyi[64], s_pxj[64], s_pyj[64];
  int tid = threadIdx.x;
  const float* Eb = E + (size_t)b * Nn * Dd;
  if (tid < 64) {
    s_pxi[tid] = P[(i0 + tid) * 2];
    s_pyi[tid] = P[(i0 + tid) * 2 + 1];
    s_pxj[tid] = P[(j0 + tid) * 2];
    s_pyj[tid] = P[(j0 + tid) * 2 + 1];
  }
  int ti = tid >> 4, tj = tid & 15;
  int ib = ti * 4, jb = tj * 4;
  float acc[4][4];
#pragma unroll
  for (int a = 0; a < 4; ++a)
#pragma unroll
    for (int c = 0; c < 4; ++c) acc[a][c] = 0.f;
  for (int kc = 0; kc < Dd; kc += 64) {
    __syncthreads();
    for (int idx = tid; idx < 64 * 64; idx += 256) {
      int ii = idx >> 6, dd = idx & 63;
      Ei_s[dd * 68 + ii] = Eb[(size_t)(i0 + ii) * Dd + kc + dd];
      Ej_s[dd * 68 + ii] = Eb[(size_t)(j0 + ii) * Dd + kc + dd];
    }
    __syncthreads();
#pragma unroll 8
    for (int kk = 0; kk < 64; ++kk) {
      const float4 a = *reinterpret_cast<const float4*>(&Ei_s[kk * 68 + ib]);
      const float4 q = *reinterpret_cast<const float4*>(&Ej_s[kk * 68 + jb]);
      acc[0][0] += a.x * q.x; acc[0][1] += a.x * q.y; acc[0][2] += a.x * q.z; acc[0][3] += a.x * q.w;
      acc[1][0] += a.y * q.x; acc[1][1] += a.y * q.y; acc[1][2] += a.y * q.z; acc[1][3] += a.y * q.w;
      acc[2][0] += a.z * q.x; acc[2][1] += a.z * q.y; acc[2][2] += a.z * q.z; acc[2][3] += a.z * q.w;
      acc[3][0] += a.w * q.x; acc[3][1] += a.w * q.y; acc[3][2] += a.w * q.z; acc[3][3] += a.w * q.w;
    }
  }
  float outv[4][4];
#pragma unroll
  for (int di = 0; di < 4; ++di) {
    float px = s_pxi[ib + di], py = s_pyi[ib + di];
#pragma unroll
    for (int dj = 0; dj < 4; ++dj) {
      float dx = px - s_pxj[jb + dj];
      float dy = py - s_pyj[jb + dj];
      float gg = 1.0f - __expf(-(dx * dx + dy * dy) * (1.0f / 18.0f));
      outv[di][dj] = acc[di][dj] * gg;
    }
  }
  size_t ob = (size_t)b * Nn * Nn;
#pragma unroll
  for (int di = 0; di < 4; ++di) {
    __half2 h01 = __floats2half2_rn(outv[di][0], outv[di][1]);
    __half2 h23 = __floats2half2_rn(outv[di][2], outv[di][3]);
    __half2* p = reinterpret_cast<__half2*>(&S[ob + (size_t)(i0 + ib + di) * Nn + j0 + jb]);
    p[0] = h01; p[1] = h23;
  }
  if (i0 != j0) {
#pragma unroll
    for (int dj = 0; dj < 4; ++dj) {
      __half2 h01 = __floats2half2_rn(outv[0][dj], outv[1][dj]);
      __half2 h23 = __floats2half2_rn(outv[2][dj], outv[3][dj]);
      __half2* p = reinterpret_cast<__half2*>(&S[ob + (size_t)(j0 + jb + dj) * Nn + i0 + ib]);
      p[0] = h01; p[1] = h23;
    }
  }
}

// ---- K8: exact top-32 per row: 2-pass radix select on fp16 keys, then exact
//      fp32 recompute of the 32 selected values from E (topv/dr/dc exact) ----
__global__ __launch_bounds__(256) void k_topk(
    const __half* __restrict__ S16, const float* __restrict__ E,
    const float* __restrict__ P, float* __restrict__ topv, int* __restrict__ topi,
    float* __restrict__ dr, float* __restrict__ dc) {
  int row = blockIdx.x;
  int b = row / Nn, irow = row % Nn;
  int tid = threadIdx.x;
  const unsigned* Sr = reinterpret_cast<const unsigned*>(S16 + (size_t)row * Nn);
  __shared__ unsigned hist[256 * 8];
  __shared__ unsigned scan_s[256];
  __shared__ unsigned bcast[2];
  __shared__ unsigned sel_eq, sel_slot;
  __shared__ int sel_idx[NTOP];
  __shared__ float drow_s;
  unsigned pk[7];                  // 2 fp16 monotone keys per u32
#pragma unroll
  for (int j = 0; j < 7; ++j) {
    int c2 = tid + 256 * j;
    unsigned u = (c2 < Nn / 2) ? Sr[c2] : 0u;
    unsigned h0 = u & 0xFFFFu, h1 = u >> 16;
    unsigned k0 = h0 ^ ((h0 & 0x8000u) ? 0xFFFFu : 0x8000u);
    unsigned k1 = h1 ^ ((h1 & 0x8000u) ? 0xFFFFu : 0x8000u);
    if (c2 >= Nn / 2) { k0 = 0u; k1 = 0u; }
    pk[j] = k0 | (k1 << 16);
  }
  if (tid == 0) { sel_eq = 0; sel_slot = 0; drow_s = 0.f; }
  unsigned prefix = 0;
  unsigned k = NTOP;
  for (int pass = 0; pass < 2; ++pass) {
    int shift = 8 - 8 * pass;
    unsigned pmask = pass ? 0xFF00u : 0u;
#pragma unroll
    for (int i = 0; i < 8; ++i) hist[tid * 8 + i] = 0;
    __syncthreads();
#pragma unroll
    for (int j = 0; j < 7; ++j) {
      unsigned k0 = pk[j] & 0xFFFFu, k1 = pk[j] >> 16;
      if ((k0 & pmask) == (prefix & pmask))
        atomicAdd(&hist[((k0 >> shift) & 255u) * 8 + (tid & 7)], 1u);
      if ((k1 & pmask) == (prefix & pmask))
        atomicAdd(&hist[((k1 >> shift) & 255u) * 8 + (tid & 7)], 1u);
    }
    __syncthreads();
    unsigned cnt = 0;
#pragma unroll
    for (int i = 0; i < 8; ++i) cnt += hist[tid * 8 + i];
    unsigned run = cnt;
    scan_s[tid] = run;
    for (int st = 1; st < 256; st <<= 1) {
      __syncthreads();
      unsigned add = (tid + st < 256) ? scan_s[tid + st] : 0u;
      __syncthreads();
      run += add;
      scan_s[tid] = run;
    }
    unsigned incl = run;
    unsigned excl = incl - cnt;
    if (excl < k && k <= incl) {
      bcast[0] = prefix | ((unsigned)tid << shift);
      bcast[1] = k - excl;
    }
    __syncthreads();
    prefix = bcast[0];
    k = bcast[1];
    __syncthreads();
  }
  unsigned T = prefix;
#pragma unroll
  for (int j = 0; j < 7; ++j) {
    int c2 = tid + 256 * j;
    if (c2 < Nn / 2) {
      unsigned k0 = pk[j] & 0xFFFFu, k1 = pk[j] >> 16;
      bool take0 = (k0 > T) || (k0 == T && atomicAdd(&sel_eq, 1u) < k);
      if (take0) { unsigned slot = atomicAdd(&sel_slot, 1u); sel_idx[slot] = 2 * c2; }
      bool take1 = (k1 > T) || (k1 == T && atomicAdd(&sel_eq, 1u) < k);
      if (take1) { unsigned slot = atomicAdd(&sel_slot, 1u); sel_idx[slot] = 2 * c2 + 1; }
    }
  }
  __syncthreads();
  // exact recompute: 8 threads per selected entry
  int sel = tid >> 3, part = tid & 7;
  int col = sel_idx[sel];
  const float* Ei = E + ((size_t)b * Nn + irow) * Dd;
  const float* Ej = E + ((size_t)b * Nn + col) * Dd;
  float v = 0.f;
#pragma unroll
  for (int d0 = 0; d0 < 16; ++d0) {
    int d = part * 16 + d0;
    v += Ei[d] * Ej[d];
  }
  v += __shfl_xor(v, 1);
  v += __shfl_xor(v, 2);
  v += __shfl_xor(v, 4);
  if (part == 0) {
    float dx = P[irow * 2] - P[col * 2];
    float dy = P[irow * 2 + 1] - P[col * 2 + 1];
    float gg = 1.0f - __expf(-(dx * dx + dy * dy) * (1.0f / 18.0f));
    v *= gg;
    topv[(size_t)row * NTOP + sel] = v;
    topi[(size_t)row * NTOP + sel] = col;
    float e = __expf(10.f * v);
    atomicAdd(&dc[b * Nn + col], e - 1.f);
    atomicAdd(&drow_s, e);
  }
  __syncthreads();
  if (tid == 0) dr[row] = (float)(Nn - NTOP) + drow_s;
}

__global__ void k_dcinit(float* __restrict__ dc) {
  int i = blockIdx.x * 256 + threadIdx.x;
  if (i < Bb * Nn) dc[i] = (float)Nn;
}

__global__ void k_inv(float* __restrict__ dr, float* __restrict__ dc) {
  int i = blockIdx.x * 256 + threadIdx.x;
  if (i < Bb * Nn) {
    dr[i] = 1.0f / dr[i];
    dc[i] = 1.0f / dc[i];
  }
}

// ---------------- K10: A0 row = invdr_i * invdc_j, then fix 32 entries -------
__global__ __launch_bounds__(256) void k_basefix(
    const float* __restrict__ invdr, const float* __restrict__ invdc,
    const float* __restrict__ topv, const int* __restrict__ topi,
    float* __restrict__ A0) {
  int row = blockIdx.x;            // b*N + i
  int b = row / Nn;
  float idr = invdr[row];
  const float4* dc4 = reinterpret_cast<const float4*>(invdc + b * Nn);
  float4* out4 = reinterpret_cast<float4*>(A0 + (size_t)row * Nn);
  for (int j = threadIdx.x; j < Nn / 4; j += 256) {
    float4 c = dc4[j];
    float4 o = {idr * c.x, idr * c.y, idr * c.z, idr * c.w};
    out4[j] = o;
  }
  __syncthreads();
  if (threadIdx.x < NTOP) {
    int gidx = row * NTOP + threadIdx.x;
    int col = topi[gidx];
    float e = __expf(10.f * topv[gidx]);
    A0[(size_t)row * Nn + col] = e * e * idr * invdc[b * Nn + col];
  }
}

extern "C" void kernel_launch(void* const* d_in, const int* in_sizes, int n_in,
                              void* d_out, int out_size, void* d_ws, size_t ws_size,
                              hipStream_t stream) {
  const float* fm     = (const float*)d_in[0];
  const float* Abank  = (const float*)d_in[1];
  const float* pw_w   = (const float*)d_in[2];
  const float* pw_b   = (const float*)d_in[3];
  const float* proj_w = (const float*)d_in[4];
  const float* proj_b = (const float*)d_in[5];
  const float* r      = (const float*)d_in[6];
  const float* Mmat   = (const float*)d_in[7];
  const float* P      = (const float*)d_in[8];
  float* out = (float*)d_out;
  float* E  = out;
  float* A0 = out + (size_t)Bb * Nn * Dd;
  // fp16 S aliases into the A0 output region (read fully by k_topk before
  // k_basefix overwrites A0) — zero extra workspace.
  __half* S16 = (__half*)A0;

  float* ws = (float*)d_ws;
  float* y     = ws;                       //  1,605,632 floats (B*D*N)
  float* zt    = ws + 1605632;             //  6,422,528 (T*B*D*K, d-major)
  float* z     = ws + 8028160;             //  6,422,528 (T*B*K*D, normalized)
  float* wct   = ws + 14450688;            //     32,768
  float* bcv   = ws + 14483456;            //        128
  float* s_arr = ws + 14483584;            //     50,176
  float* g     = ws + 14533760;            //    401,408
  float* topv  = ws + 14935168;            //    401,408
  int*   topi  = (int*)(ws + 15336576);    //    401,408
  float* dr    = ws + 15737984;            //     12,544
  float* dc    = ws + 15750528;            //     12,544

  hipLaunchKernelGGL(k_wc, dim3(Cc), dim3(128), 0, stream, pw_w, pw_b, proj_w, proj_b, wct, bcv);
  hipLaunchKernelGGL(k_mix, dim3(448), dim3(256), 0, stream, fm, wct, y);
  hipLaunchKernelGGL(k_fused_pool, dim3(2048), dim3(256), 0, stream, y, Abank, bcv, zt);
  hipLaunchKernelGGL(k_znorm, dim3(64 * 14), dim3(256), 0, stream, zt, r, z, s_arr);
  hipLaunchKernelGGL(k_gemb, dim3(Bb * Kk), dim3(128), 0, stream, z, s_arr, g);
  hipLaunchKernelGGL(k_E, dim3(Bb * Nn), dim3(64), 0, stream, Mmat, g, E);
  hipLaunchKernelGGL(k_saff, dim3(Bb * 1225), dim3(256), 0, stream, E, P, S16);
  hipLaunchKernelGGL(k_dcinit, dim3(49), dim3(256), 0, stream, dc);
  hipLaunchKernelGGL(k_topk, dim3(Bb * Nn), dim3(256), 0, stream, S16, E, P, topv, topi, dr, dc);
  hipLaunchKernelGGL(k_inv, dim3(49), dim3(256), 0, stream, dr, dc);
  hipLaunchKernelGGL(k_basefix, dim3(Bb * Nn), dim3(256), 0, stream, dr, dc, topv, topi, A0);
}

// Round 4
// 489.819 us; speedup vs baseline: 1.4238x; 1.0531x over previous
//
#include <hip/hip_runtime.h>
#include <hip/hip_bf16.h>
#include <hip/hip_fp16.h>

#define Hh 56
#define Ww 56
#define Cc 256
#define Tt 16
#define Bb 4
#define Nn 3136
#define Kk 784
#define KX 28
#define Dd 128
#define Mc 64
#define NTOP 32

typedef __attribute__((ext_vector_type(8))) _Float16 f16x8;
typedef __attribute__((ext_vector_type(4))) float f32x4;

// ---------------- K3a: combined weight Wc^T [c][d] and bias bc ---------------
__global__ __launch_bounds__(128) void k_wc(
    const float* __restrict__ pw_w, const float* __restrict__ pw_b,
    const float* __restrict__ proj_w, const float* __restrict__ proj_b,
    float* __restrict__ wct, float* __restrict__ bc) {
  int c = blockIdx.x;
  int d = threadIdx.x;
  float acc = 0.f;
  for (int m = 0; m < Mc; ++m) acc += proj_w[d * Mc + m] * pw_w[m * Cc + c];
  wct[c * Dd + d] = acc;
  if (c == 0) {
    float bb = proj_b[d];
    for (int m = 0; m < Mc; ++m) bb += proj_w[d * Mc + m] * pw_b[m];
    bc[d] = bb;
  }
}

// ---- K_mix: y[b][d][n] = sum_c fm[b][c][n] * wct[c][d]  (channel mix FIRST;
//      commutes with warp+pool since those are per-channel spatial linear ops)
__global__ __launch_bounds__(256) void k_mix(
    const float* __restrict__ fm, const float* __restrict__ wct, float* __restrict__ y) {
  int blk = blockIdx.x;
  int b = blk / 112;
  int n0 = (blk % 112) * 28;
  int tid = threadIdx.x;
  int d = tid & 127;
  int ng = tid >> 7;               // 0..1
  __shared__ float fm_s[64 * 28];
  __shared__ float wc_s[64 * Dd];
  float acc[14];
#pragma unroll
  for (int j = 0; j < 14; ++j) acc[j] = 0.f;
  const float* fb = fm + (size_t)b * Cc * Nn;
  for (int c0 = 0; c0 < Cc; c0 += 64) {
    for (int i = tid; i < 64 * 28; i += 256) {
      int c = i / 28, kx = i - c * 28;
      fm_s[i] = fb[(size_t)(c0 + c) * Nn + n0 + kx];
    }
    for (int i = tid; i < 64 * Dd; i += 256) wc_s[i] = wct[c0 * Dd + i];
    __syncthreads();
    for (int c = 0; c < 64; ++c) {
      float w = wc_s[c * Dd + d];
#pragma unroll
      for (int j = 0; j < 14; ++j) acc[j] += fm_s[c * 28 + ng * 14 + j] * w;
    }
    __syncthreads();
  }
  float* yo = y + ((size_t)b * Dd + d) * Nn + n0 + ng * 14;
#pragma unroll
  for (int j = 0; j < 14; ++j) yo[j] = acc[j];
}

// ---- K1: fused affine warp + bilinear + 9x9/s2 zero-pad avg-pool on mixed y
//      writes zt[((t*B+b)*D + d)*K + k] = pooled + bc[d]   (d-major, k-contig)
__global__ __launch_bounds__(256) void k_fused_pool(
    const float* __restrict__ y, const float* __restrict__ Abank,
    const float* __restrict__ bc, float* __restrict__ zt) {
  int idx = blockIdx.x;
  int b = idx & 3;
  int dg = (idx >> 2) & 31;
  int t = idx >> 7;
  __shared__ float wsm[3136];
  __shared__ float rowp[1568];
  int tid = threadIdx.x;
  const float* A = Abank + t * 6;
  float a00 = A[0], a01 = A[1], a02 = A[2], a10 = A[3], a11 = A[4], a12 = A[5];
  int off[13];
  float wxa[13], wya[13];
#pragma unroll
  for (int j = 0; j < 13; ++j) {
    int e = tid + 256 * j;
    if (e < 3136) {
      int h = e / 56, w = e - h * 56;
      float gx = (2.0f * w + 1.0f) / 56.0f - 1.0f;
      float gy = (2.0f * h + 1.0f) / 56.0f - 1.0f;
      float u = a00 * gx + a01 * gy + a02;
      float v = a10 * gx + a11 * gy + a12;
      float ix = ((u + 1.0f) * 56.0f - 1.0f) * 0.5f;
      float iy = ((v + 1.0f) * 56.0f - 1.0f) * 0.5f;
      float x0f = floorf(ix), y0f = floorf(iy);
      wxa[j] = ix - x0f;
      wya[j] = iy - y0f;
      int x0 = (int)x0f, y0 = (int)y0f;
      int x0c = min(max(x0, 0), 55), x1c = min(max(x0 + 1, 0), 55);
      int y0c = min(max(y0, 0), 55), y1c = min(max(y0 + 1, 0), 55);
      off[j] = (y0c * 56 + x0c) | ((x1c - x0c) << 12) | ((y1c - y0c) << 13);
    }
  }
  for (int dd = 0; dd < 4; ++dd) {
    int d = dg * 4 + dd;
    const float* fc = y + ((size_t)b * Dd + d) * Nn;
    float bias = bc[d];
#pragma unroll
    for (int j = 0; j < 13; ++j) {
      int e = tid + 256 * j;
      if (e < 3136) {
        int pk = off[j];
        int base = pk & 4095;
        int dx = (pk >> 12) & 1;
        int dyy = (pk & (1 << 13)) ? 56 : 0;
        float v00 = fc[base], v01 = fc[base + dx];
        float v10 = fc[base + dyy], v11 = fc[base + dyy + dx];
        float wx = wxa[j], wy = wya[j];
        float top = v00 + wx * (v01 - v00);
        float bot = v10 + wx * (v11 - v10);
        wsm[e] = top + wy * (bot - top);
      }
    }
    __syncthreads();
    for (int e = tid; e < 1568; e += 256) {
      int h = e / 28, kx = e - h * 28;
      int xs = 2 * kx - 4;
      int lo = max(xs, 0), hi = min(xs + 8, 55);
      float s = 0.f;
      const float* wr = wsm + h * 56;
      for (int x = lo; x <= hi; ++x) s += wr[x];
      rowp[e] = s;
    }
    __syncthreads();
    float* zo = zt + ((size_t)(t * Bb + b) * Dd + d) * Kk;
    for (int e = tid; e < 784; e += 256) {
      int ky = e / 28, kx = e - ky * 28;
      int ys = 2 * ky - 4;
      int lo = max(ys, 0), hi = min(ys + 8, 55);
      float s = 0.f;
      for (int h = lo; h <= hi; ++h) s += rowp[h * 28 + kx];
      zo[e] = s * (1.0f / 81.0f) + bias;
    }
    __syncthreads();
  }
}

// ---- K4: transpose zt -> z (normalized, [tb][k][d]) + s = zn . r ------------
__global__ __launch_bounds__(256) void k_znorm(
    const float* __restrict__ zt, const float* __restrict__ r,
    float* __restrict__ z, float* __restrict__ s_arr) {
  int tb = blockIdx.x / 14;
  int k0 = (blockIdx.x % 14) * 56;
  int tid = threadIdx.x;
  __shared__ float ls[56 * 129];
  const float* zb = zt + (size_t)tb * Dd * Kk + k0;
  for (int i = tid; i < Dd * 56; i += 256) {
    int d = i / 56, kk = i - d * 56;
    ls[kk * 129 + d] = zb[(size_t)d * Kk + kk];
  }
  int lane = tid & 63;
  int wv = tid >> 6;               // 0..3
  float r0 = r[lane], r1 = r[lane + 64];
  __syncthreads();
  for (int p = 0; p < 14; ++p) {
    int k = p * 4 + wv;
    float z0 = ls[k * 129 + lane];
    float z1 = ls[k * 129 + 64 + lane];
    float ss = z0 * z0 + z1 * z1;
    for (int off = 32; off; off >>= 1) ss += __shfl_xor(ss, off);
    float inv = 1.0f / fmaxf(sqrtf(ss), 1e-6f);
    z0 *= inv; z1 *= inv;
    float* zr = z + ((size_t)tb * Kk + k0 + k) * Dd;
    zr[lane] = z0;
    zr[lane + 64] = z1;
    float sd = z0 * r0 + z1 * r1;
    for (int off = 32; off; off >>= 1) sd += __shfl_xor(sd, off);
    if (lane == 0) s_arr[(size_t)tb * Kk + k0 + k] = sd;
  }
}

// ---------------- K5: softmax over T, g_emb ----------------------------------
__global__ __launch_bounds__(128) void k_gemb(
    const float* __restrict__ z, const float* __restrict__ s_arr, float* __restrict__ g) {
  int blk = blockIdx.x;            // b*784 + k
  int b = blk / Kk, k = blk % Kk;
  int d = threadIdx.x;
  float sv[Tt];
  float mx = -3.4e38f;
#pragma unroll
  for (int t = 0; t < Tt; ++t) {
    sv[t] = s_arr[(t * Bb + b) * Kk + k];
    mx = fmaxf(mx, sv[t]);
  }
  float sum = 0.f;
#pragma unroll
  for (int t = 0; t < Tt; ++t) {
    sv[t] = expf(10.0f * (sv[t] - mx));
    sum += sv[t];
  }
  float isum = 1.0f / sum;
  float acc = 0.f;
#pragma unroll
  for (int t = 0; t < Tt; ++t)
    acc += sv[t] * isum * z[((size_t)(t * Bb + b) * Kk + k) * Dd + d];
  g[((size_t)b * Kk + k) * Dd + d] = acc;
}

// ---- K6: E = normalize(M @ g), also emits fp16 copy for the MFMA k_saff -----
__global__ __launch_bounds__(64) void k_E(
    const float* __restrict__ Mmat, const float* __restrict__ g,
    float* __restrict__ E, _Float16* __restrict__ E16) {
  int row = blockIdx.x;            // b*N + n
  int b = row / Nn, n = row % Nn;
  int y = n / Ww, x = n % Ww;
  int x0 = x >> 1, y0 = y >> 1;
  int x1 = min(x0 + 1, 27), y1 = min(y0 + 1, 27);
  bool hx = (x1 != x0), hy = (y1 != y0);
  int k00 = y0 * 28 + x0, k01 = y0 * 28 + x1, k10 = y1 * 28 + x0, k11 = y1 * 28 + x1;
  const float* Mr = Mmat + (size_t)n * Kk;
  float m00 = Mr[k00];
  float m01 = hx ? Mr[k01] : 0.f;
  float m10 = hy ? Mr[k10] : 0.f;
  float m11 = (hx && hy) ? Mr[k11] : 0.f;
  const float* gb = g + (size_t)b * Kk * Dd;
  int lane = threadIdx.x;
  int l2 = lane + 64;
  float a0 = m00 * gb[k00 * Dd + lane] + m01 * gb[k01 * Dd + lane] +
             m10 * gb[k10 * Dd + lane] + m11 * gb[k11 * Dd + lane];
  float a1 = m00 * gb[k00 * Dd + l2] + m01 * gb[k01 * Dd + l2] +
             m10 * gb[k10 * Dd + l2] + m11 * gb[k11 * Dd + l2];
  float ss = a0 * a0 + a1 * a1;
  for (int off = 32; off; off >>= 1) ss += __shfl_xor(ss, off);
  float inv = 1.0f / fmaxf(sqrtf(ss), 1e-6f);
  float e0 = a0 * inv, e1 = a1 * inv;
  E[(size_t)row * Dd + lane] = e0;
  E[(size_t)row * Dd + l2] = e1;
  E16[(size_t)row * Dd + lane] = (_Float16)e0;
  E16[(size_t)row * Dd + l2] = (_Float16)e1;
}

// ---- K7: Saff = (E E^T) * G -> fp16 via MFMA f16 (fp32 accum), no LDS -------
// 64x64 tile/block, 4 waves each a 32x32 quadrant (2x2 mfma_f32_16x16x32_f16).
// Fragments loaded straight from L2-resident E16; G from index-derived coords.
__global__ __launch_bounds__(256) void k_saff(
    const _Float16* __restrict__ E16, __half* __restrict__ S) {
  int blk = blockIdx.x;
  int b = blk / 1225;
  int rem = blk % 1225;
  int ti0 = (int)((sqrtf(8.f * rem + 1.f) - 1.f) * 0.5f);
  while ((ti0 + 1) * (ti0 + 2) / 2 <= rem) ++ti0;
  while (ti0 * (ti0 + 1) / 2 > rem) --ti0;
  int tj0 = rem - ti0 * (ti0 + 1) / 2;   // tj0 <= ti0
  int i0 = ti0 * 64, j0 = tj0 * 64;
  int wave = threadIdx.x >> 6, lane = threadIdx.x & 63;
  int wr = wave >> 1, wc = wave & 1;
  int lr = lane & 15, lk = lane >> 4;    // frag row/col, k-group
  int ibase = i0 + wr * 32;
  int jbase = j0 + wc * 32;
  const _Float16* Eb = E16 + (size_t)b * Nn * Dd;
  f32x4 acc00 = {0.f, 0.f, 0.f, 0.f};
  f32x4 acc01 = acc00, acc10 = acc00, acc11 = acc00;
#pragma unroll
  for (int ks = 0; ks < 4; ++ks) {
    int ko = ks * 32 + lk * 8;
    f16x8 a0 = *reinterpret_cast<const f16x8*>(Eb + (size_t)(ibase + lr) * Dd + ko);
    f16x8 a1 = *reinterpret_cast<const f16x8*>(Eb + (size_t)(ibase + 16 + lr) * Dd + ko);
    f16x8 b0 = *reinterpret_cast<const f16x8*>(Eb + (size_t)(jbase + lr) * Dd + ko);
    f16x8 b1 = *reinterpret_cast<const f16x8*>(Eb + (size_t)(jbase + 16 + lr) * Dd + ko);
    acc00 = __builtin_amdgcn_mfma_f32_16x16x32_f16(a0, b0, acc00, 0, 0, 0);
    acc01 = __builtin_amdgcn_mfma_f32_16x16x32_f16(a0, b1, acc01, 0, 0, 0);
    acc10 = __builtin_amdgcn_mfma_f32_16x16x32_f16(a1, b0, acc10, 0, 0, 0);
    acc11 = __builtin_amdgcn_mfma_f32_16x16x32_f16(a1, b1, acc11, 0, 0, 0);
  }
  size_t ob = (size_t)b * Nn * Nn;
  int gj[2];
  float xj[2], yj[2];
#pragma unroll
  for (int tj = 0; tj < 2; ++tj) {
    gj[tj] = jbase + tj * 16 + lr;
    int yv = gj[tj] / 56;
    yj[tj] = (float)yv;
    xj[tj] = (float)(gj[tj] - yv * 56);
  }
  bool mirror = (i0 != j0);
#pragma unroll
  for (int ti = 0; ti < 2; ++ti) {
#pragma unroll
    for (int q = 0; q < 4; ++q) {
      int gi = ibase + ti * 16 + lk * 4 + q;
      int yiv = gi / 56;
      float yi = (float)yiv;
      float xi = (float)(gi - yiv * 56);
#pragma unroll
      for (int tj = 0; tj < 2; ++tj) {
        float a;
        if (ti == 0 && tj == 0) a = acc00[q];
        else if (ti == 0 && tj == 1) a = acc01[q];
        else if (ti == 1 && tj == 0) a = acc10[q];
        else a = acc11[q];
        float dx = xi - xj[tj];
        float dy = yi - yj[tj];
        float gg = 1.0f - __expf(-(dx * dx + dy * dy) * (1.0f / 18.0f));
        __half hv = __float2half(a * gg);
        S[ob + (size_t)gi * Nn + gj[tj]] = hv;
        if (mirror) S[ob + (size_t)gj[tj] * Nn + gi] = hv;
      }
    }
  }
}

// ---- K8: exact top-32 per row: 2-pass radix select on fp16 keys, then exact
//      fp32 recompute of the 32 selected values from E (topv/dr/dc exact) ----
__global__ __launch_bounds__(256) void k_topk(
    const __half* __restrict__ S16, const float* __restrict__ E,
    const float* __restrict__ P, float* __restrict__ topv, int* __restrict__ topi,
    float* __restrict__ dr, float* __restrict__ dc) {
  int row = blockIdx.x;
  int b = row / Nn, irow = row % Nn;
  int tid = threadIdx.x;
  const unsigned* Sr = reinterpret_cast<const unsigned*>(S16 + (size_t)row * Nn);
  __shared__ unsigned hist[256 * 8];
  __shared__ unsigned scan_s[256];
  __shared__ unsigned bcast[2];
  __shared__ unsigned sel_eq, sel_slot;
  __shared__ int sel_idx[NTOP];
  __shared__ float drow_s;
  unsigned pk[7];                  // 2 fp16 monotone keys per u32
#pragma unroll
  for (int j = 0; j < 7; ++j) {
    int c2 = tid + 256 * j;
    unsigned u = (c2 < Nn / 2) ? Sr[c2] : 0u;
    unsigned h0 = u & 0xFFFFu, h1 = u >> 16;
    unsigned k0 = h0 ^ ((h0 & 0x8000u) ? 0xFFFFu : 0x8000u);
    unsigned k1 = h1 ^ ((h1 & 0x8000u) ? 0xFFFFu : 0x8000u);
    if (c2 >= Nn / 2) { k0 = 0u; k1 = 0u; }
    pk[j] = k0 | (k1 << 16);
  }
  if (tid == 0) { sel_eq = 0; sel_slot = 0; drow_s = 0.f; }
  unsigned prefix = 0;
  unsigned k = NTOP;
  for (int pass = 0; pass < 2; ++pass) {
    int shift = 8 - 8 * pass;
    unsigned pmask = pass ? 0xFF00u : 0u;
#pragma unroll
    for (int i = 0; i < 8; ++i) hist[tid * 8 + i] = 0;
    __syncthreads();
#pragma unroll
    for (int j = 0; j < 7; ++j) {
      unsigned k0 = pk[j] & 0xFFFFu, k1 = pk[j] >> 16;
      if ((k0 & pmask) == (prefix & pmask))
        atomicAdd(&hist[((k0 >> shift) & 255u) * 8 + (tid & 7)], 1u);
      if ((k1 & pmask) == (prefix & pmask))
        atomicAdd(&hist[((k1 >> shift) & 255u) * 8 + (tid & 7)], 1u);
    }
    __syncthreads();
    unsigned cnt = 0;
#pragma unroll
    for (int i = 0; i < 8; ++i) cnt += hist[tid * 8 + i];
    unsigned run = cnt;
    scan_s[tid] = run;
    for (int st = 1; st < 256; st <<= 1) {
      __syncthreads();
      unsigned add = (tid + st < 256) ? scan_s[tid + st] : 0u;
      __syncthreads();
      run += add;
      scan_s[tid] = run;
    }
    unsigned incl = run;
    unsigned excl = incl - cnt;
    if (excl < k && k <= incl) {
      bcast[0] = prefix | ((unsigned)tid << shift);
      bcast[1] = k - excl;
    }
    __syncthreads();
    prefix = bcast[0];
    k = bcast[1];
    __syncthreads();
  }
  unsigned T = prefix;
#pragma unroll
  for (int j = 0; j < 7; ++j) {
    int c2 = tid + 256 * j;
    if (c2 < Nn / 2) {
      unsigned k0 = pk[j] & 0xFFFFu, k1 = pk[j] >> 16;
      bool take0 = (k0 > T) || (k0 == T && atomicAdd(&sel_eq, 1u) < k);
      if (take0) { unsigned slot = atomicAdd(&sel_slot, 1u); sel_idx[slot] = 2 * c2; }
      bool take1 = (k1 > T) || (k1 == T && atomicAdd(&sel_eq, 1u) < k);
      if (take1) { unsigned slot = atomicAdd(&sel_slot, 1u); sel_idx[slot] = 2 * c2 + 1; }
    }
  }
  __syncthreads();
  // exact recompute: 8 threads per selected entry
  int sel = tid >> 3, part = tid & 7;
  int col = sel_idx[sel];
  const float* Ei = E + ((size_t)b * Nn + irow) * Dd;
  const float* Ej = E + ((size_t)b * Nn + col) * Dd;
  float v = 0.f;
#pragma unroll
  for (int d0 = 0; d0 < 16; ++d0) {
    int d = part * 16 + d0;
    v += Ei[d] * Ej[d];
  }
  v += __shfl_xor(v, 1);
  v += __shfl_xor(v, 2);
  v += __shfl_xor(v, 4);
  if (part == 0) {
    float dx = P[irow * 2] - P[col * 2];
    float dy = P[irow * 2 + 1] - P[col * 2 + 1];
    float gg = 1.0f - __expf(-(dx * dx + dy * dy) * (1.0f / 18.0f));
    v *= gg;
    topv[(size_t)row * NTOP + sel] = v;
    topi[(size_t)row * NTOP + sel] = col;
    float e = __expf(10.f * v);
    atomicAdd(&dc[b * Nn + col], e - 1.f);
    atomicAdd(&drow_s, e);
  }
  __syncthreads();
  if (tid == 0) dr[row] = (float)(Nn - NTOP) + drow_s;
}

__global__ void k_dcinit(float* __restrict__ dc) {
  int i = blockIdx.x * 256 + threadIdx.x;
  if (i < Bb * Nn) dc[i] = (float)Nn;
}

__global__ void k_inv(float* __restrict__ dr, float* __restrict__ dc) {
  int i = blockIdx.x * 256 + threadIdx.x;
  if (i < Bb * Nn) {
    dr[i] = 1.0f / dr[i];
    dc[i] = 1.0f / dc[i];
  }
}

// ---------------- K10: A0 row = invdr_i * invdc_j, then fix 32 entries -------
__global__ __launch_bounds__(256) void k_basefix(
    const float* __restrict__ invdr, const float* __restrict__ invdc,
    const float* __restrict__ topv, const int* __restrict__ topi,
    float* __restrict__ A0) {
  int row = blockIdx.x;            // b*N + i
  int b = row / Nn;
  float idr = invdr[row];
  const float4* dc4 = reinterpret_cast<const float4*>(invdc + b * Nn);
  float4* out4 = reinterpret_cast<float4*>(A0 + (size_t)row * Nn);
  for (int j = threadIdx.x; j < Nn / 4; j += 256) {
    float4 c = dc4[j];
    float4 o = {idr * c.x, idr * c.y, idr * c.z, idr * c.w};
    out4[j] = o;
  }
  __syncthreads();
  if (threadIdx.x < NTOP) {
    int gidx = row * NTOP + threadIdx.x;
    int col = topi[gidx];
    float e = __expf(10.f * topv[gidx]);
    A0[(size_t)row * Nn + col] = e * e * idr * invdc[b * Nn + col];
  }
}

extern "C" void kernel_launch(void* const* d_in, const int* in_sizes, int n_in,
                              void* d_out, int out_size, void* d_ws, size_t ws_size,
                              hipStream_t stream) {
  const float* fm     = (const float*)d_in[0];
  const float* Abank  = (const float*)d_in[1];
  const float* pw_w   = (const float*)d_in[2];
  const float* pw_b   = (const float*)d_in[3];
  const float* proj_w = (const float*)d_in[4];
  const float* proj_b = (const float*)d_in[5];
  const float* r      = (const float*)d_in[6];
  const float* Mmat   = (const float*)d_in[7];
  const float* P      = (const float*)d_in[8];
  float* out = (float*)d_out;
  float* E  = out;
  float* A0 = out + (size_t)Bb * Nn * Dd;
  // fp16 S aliases into the A0 output region (read fully by k_topk before
  // k_basefix overwrites A0) — zero extra workspace.
  __half* S16 = (__half*)A0;

  float* ws = (float*)d_ws;
  float* y     = ws;                       //  1,605,632 floats (B*D*N)
  float* zt    = ws + 1605632;             //  6,422,528 (T*B*D*K, d-major)
  float* z     = ws + 8028160;             //  6,422,528 (T*B*K*D, normalized)
  float* wct   = ws + 14450688;            //     32,768
  float* bcv   = ws + 14483456;            //        128
  float* s_arr = ws + 14483584;            //     50,176
  float* g     = ws + 14533760;            //    401,408
  float* topv  = ws + 14935168;            //    401,408
  int*   topi  = (int*)(ws + 15336576);    //    401,408
  float* dr    = ws + 15737984;            //     12,544
  float* dc    = ws + 15750528;            //     12,544
  _Float16* E16 = (_Float16*)(ws + 15763072); // 1,605,632 halves

  hipLaunchKernelGGL(k_wc, dim3(Cc), dim3(128), 0, stream, pw_w, pw_b, proj_w, proj_b, wct, bcv);
  hipLaunchKernelGGL(k_mix, dim3(448), dim3(256), 0, stream, fm, wct, y);
  hipLaunchKernelGGL(k_fused_pool, dim3(2048), dim3(256), 0, stream, y, Abank, bcv, zt);
  hipLaunchKernelGGL(k_znorm, dim3(64 * 14), dim3(256), 0, stream, zt, r, z, s_arr);
  hipLaunchKernelGGL(k_gemb, dim3(Bb * Kk), dim3(128), 0, stream, z, s_arr, g);
  hipLaunchKernelGGL(k_E, dim3(Bb * Nn), dim3(64), 0, stream, Mmat, g, E, E16);
  hipLaunchKernelGGL(k_saff, dim3(Bb * 1225), dim3(256), 0, stream, E16, S16);
  hipLaunchKernelGGL(k_dcinit, dim3(49), dim3(256), 0, stream, dc);
  hipLaunchKernelGGL(k_topk, dim3(Bb * Nn), dim3(256), 0, stream, S16, E, P, topv, topi, dr, dc);
  hipLaunchKernelGGL(k_inv, dim3(49), dim3(256), 0, stream, dr, dc);
  hipLaunchKernelGGL(k_basefix, dim3(Bb * Nn), dim3(256), 0, stream, dr, dc, topv, topi, A0);
}

// Round 5
// 436.421 us; speedup vs baseline: 1.5980x; 1.1224x over previous
//
#include <hip/hip_runtime.h>
#include <hip/hip_bf16.h>
#include <hip/hip_fp16.h>

#define Hh 56
#define Ww 56
#define Cc 256
#define Tt 16
#define Bb 4
#define Nn 3136
#define Kk 784
#define KX 28
#define Dd 128
#define Mc 64
#define NTOP 32

typedef __attribute__((ext_vector_type(8))) _Float16 f16x8;
typedef __attribute__((ext_vector_type(4))) float f32x4;

// ---------------- K3a: combined weight Wc^T [c][d] and bias bc ---------------
__global__ __launch_bounds__(128) void k_wc(
    const float* __restrict__ pw_w, const float* __restrict__ pw_b,
    const float* __restrict__ proj_w, const float* __restrict__ proj_b,
    float* __restrict__ wct, float* __restrict__ bc) {
  int c = blockIdx.x;
  int d = threadIdx.x;
  float acc = 0.f;
  for (int m = 0; m < Mc; ++m) acc += proj_w[d * Mc + m] * pw_w[m * Cc + c];
  wct[c * Dd + d] = acc;
  if (c == 0) {
    float bb = proj_b[d];
    for (int m = 0; m < Mc; ++m) bb += proj_w[d * Mc + m] * pw_b[m];
    bc[d] = bb;
  }
}

// ---- K_mix: channel mix FIRST. Writes PAIR-INTERLEAVED layout:
//      y2[((b*64 + d/2)*N + n)*2 + (d&1)]  so k_fused_pool taps are float2.
__global__ __launch_bounds__(256) void k_mix(
    const float* __restrict__ fm, const float* __restrict__ wct, float* __restrict__ y) {
  int blk = blockIdx.x;
  int b = blk / 112;
  int n0 = (blk % 112) * 28;
  int tid = threadIdx.x;
  int d = tid & 127;
  int ng = tid >> 7;               // 0..1
  __shared__ float fm_s[64 * 28];
  __shared__ float wc_s[64 * Dd];
  float acc[14];
#pragma unroll
  for (int j = 0; j < 14; ++j) acc[j] = 0.f;
  const float* fb = fm + (size_t)b * Cc * Nn;
  for (int c0 = 0; c0 < Cc; c0 += 64) {
    for (int i = tid; i < 64 * 28; i += 256) {
      int c = i / 28, kx = i - c * 28;
      fm_s[i] = fb[(size_t)(c0 + c) * Nn + n0 + kx];
    }
    for (int i = tid; i < 64 * Dd; i += 256) wc_s[i] = wct[c0 * Dd + i];
    __syncthreads();
    for (int c = 0; c < 64; ++c) {
      float w = wc_s[c * Dd + d];
#pragma unroll
      for (int j = 0; j < 14; ++j) acc[j] += fm_s[c * 28 + ng * 14 + j] * w;
    }
    __syncthreads();
  }
  size_t base = (((size_t)b * 64 + (d >> 1)) * Nn + n0 + ng * 14) * 2 + (d & 1);
#pragma unroll
  for (int j = 0; j < 14; ++j) y[base + 2 * j] = acc[j];
}

// ---- K1: fused warp+bilinear+9x9/s2 pool, 2 channels at a time via float2 ---
// grid: b(4) x pg(32, 2 pairs each) x t(16) = 2048 blocks, 256 thr
// Tap loads are 8B (2 channels) -> half the global ops of the scalar version.
__global__ __launch_bounds__(256) void k_fused_pool(
    const float* __restrict__ yraw, const float* __restrict__ Abank,
    const float* __restrict__ bc, float* __restrict__ zt) {
  const float2* y2 = reinterpret_cast<const float2*>(yraw);
  int idx = blockIdx.x;
  int b = idx & 3;
  int pg = (idx >> 2) & 31;
  int t = idx >> 7;
  __shared__ float2 wsm[3136];
  __shared__ float2 rowp[1568];
  int tid = threadIdx.x;
  const float* A = Abank + t * 6;
  float a00 = A[0], a01 = A[1], a02 = A[2], a10 = A[3], a11 = A[4], a12 = A[5];
  int off[13];
  float wxa[13], wya[13];
#pragma unroll
  for (int j = 0; j < 13; ++j) {
    int e = tid + 256 * j;
    if (e < 3136) {
      int h = e / 56, w = e - h * 56;
      float gx = (2.0f * w + 1.0f) / 56.0f - 1.0f;
      float gy = (2.0f * h + 1.0f) / 56.0f - 1.0f;
      float u = a00 * gx + a01 * gy + a02;
      float v = a10 * gx + a11 * gy + a12;
      float ix = ((u + 1.0f) * 56.0f - 1.0f) * 0.5f;
      float iy = ((v + 1.0f) * 56.0f - 1.0f) * 0.5f;
      float x0f = floorf(ix), y0f = floorf(iy);
      wxa[j] = ix - x0f;
      wya[j] = iy - y0f;
      int x0 = (int)x0f, y0 = (int)y0f;
      int x0c = min(max(x0, 0), 55), x1c = min(max(x0 + 1, 0), 55);
      int y0c = min(max(y0, 0), 55), y1c = min(max(y0 + 1, 0), 55);
      off[j] = (y0c * 56 + x0c) | ((x1c - x0c) << 12) | ((y1c - y0c) << 13);
    }
  }
  for (int pp = 0; pp < 2; ++pp) {
    int dp = pg * 2 + pp;                       // channel pair 0..63
    const float2* fc = y2 + ((size_t)b * 64 + dp) * Nn;
    float b0 = bc[dp * 2], b1 = bc[dp * 2 + 1];
#pragma unroll
    for (int j = 0; j < 13; ++j) {
      int e = tid + 256 * j;
      if (e < 3136) {
        int pk = off[j];
        int base = pk & 4095;
        int dx = (pk >> 12) & 1;
        int dyy = (pk & (1 << 13)) ? 56 : 0;
        float2 v00 = fc[base], v01 = fc[base + dx];
        float2 v10 = fc[base + dyy], v11 = fc[base + dyy + dx];
        float wx = wxa[j], wy = wya[j];
        float tx = v00.x + wx * (v01.x - v00.x);
        float bx = v10.x + wx * (v11.x - v10.x);
        float ty = v00.y + wx * (v01.y - v00.y);
        float by = v10.y + wx * (v11.y - v10.y);
        float2 o;
        o.x = tx + wy * (bx - tx);
        o.y = ty + wy * (by - ty);
        wsm[e] = o;
      }
    }
    __syncthreads();
    for (int e = tid; e < 1568; e += 256) {
      int h = e / 28, kx = e - h * 28;
      int xs = 2 * kx - 4;
      int lo = max(xs, 0), hi = min(xs + 8, 55);
      float sx = 0.f, sy = 0.f;
      const float2* wr = wsm + h * 56;
      for (int x = lo; x <= hi; ++x) { float2 v = wr[x]; sx += v.x; sy += v.y; }
      float2 o; o.x = sx; o.y = sy;
      rowp[e] = o;
    }
    __syncthreads();
    float* zo0 = zt + ((size_t)(t * Bb + b) * Dd + dp * 2) * Kk;
    float* zo1 = zo0 + Kk;
    for (int e = tid; e < 784; e += 256) {
      int ky = e / 28, kx = e - ky * 28;
      int ys = 2 * ky - 4;
      int lo = max(ys, 0), hi = min(ys + 8, 55);
      float sx = 0.f, sy = 0.f;
      for (int h = lo; h <= hi; ++h) { float2 rv = rowp[h * 28 + kx]; sx += rv.x; sy += rv.y; }
      zo0[e] = sx * (1.0f / 81.0f) + b0;
      zo1[e] = sy * (1.0f / 81.0f) + b1;
    }
    __syncthreads();
  }
}

// ---- K4: transpose zt -> z (normalized, [tb][k][d]) + s = zn . r ------------
__global__ __launch_bounds__(256) void k_znorm(
    const float* __restrict__ zt, const float* __restrict__ r,
    float* __restrict__ z, float* __restrict__ s_arr) {
  int tb = blockIdx.x / 14;
  int k0 = (blockIdx.x % 14) * 56;
  int tid = threadIdx.x;
  __shared__ float ls[56 * 129];
  const float* zb = zt + (size_t)tb * Dd * Kk + k0;
  for (int i = tid; i < Dd * 56; i += 256) {
    int d = i / 56, kk = i - d * 56;
    ls[kk * 129 + d] = zb[(size_t)d * Kk + kk];
  }
  int lane = tid & 63;
  int wv = tid >> 6;               // 0..3
  float r0 = r[lane], r1 = r[lane + 64];
  __syncthreads();
  for (int p = 0; p < 14; ++p) {
    int k = p * 4 + wv;
    float z0 = ls[k * 129 + lane];
    float z1 = ls[k * 129 + 64 + lane];
    float ss = z0 * z0 + z1 * z1;
    for (int off = 32; off; off >>= 1) ss += __shfl_xor(ss, off);
    float inv = 1.0f / fmaxf(sqrtf(ss), 1e-6f);
    z0 *= inv; z1 *= inv;
    float* zr = z + ((size_t)tb * Kk + k0 + k) * Dd;
    zr[lane] = z0;
    zr[lane + 64] = z1;
    float sd = z0 * r0 + z1 * r1;
    for (int off = 32; off; off >>= 1) sd += __shfl_xor(sd, off);
    if (lane == 0) s_arr[(size_t)tb * Kk + k0 + k] = sd;
  }
}

// ---------------- K5: softmax over T, g_emb ----------------------------------
__global__ __launch_bounds__(128) void k_gemb(
    const float* __restrict__ z, const float* __restrict__ s_arr, float* __restrict__ g) {
  int blk = blockIdx.x;            // b*784 + k
  int b = blk / Kk, k = blk % Kk;
  int d = threadIdx.x;
  float sv[Tt];
  float mx = -3.4e38f;
#pragma unroll
  for (int t = 0; t < Tt; ++t) {
    sv[t] = s_arr[(t * Bb + b) * Kk + k];
    mx = fmaxf(mx, sv[t]);
  }
  float sum = 0.f;
#pragma unroll
  for (int t = 0; t < Tt; ++t) {
    sv[t] = expf(10.0f * (sv[t] - mx));
    sum += sv[t];
  }
  float isum = 1.0f / sum;
  float acc = 0.f;
#pragma unroll
  for (int t = 0; t < Tt; ++t)
    acc += sv[t] * isum * z[((size_t)(t * Bb + b) * Kk + k) * Dd + d];
  g[((size_t)b * Kk + k) * Dd + d] = acc;
}

// ---- K6: E = normalize(M @ g), also emits fp16 copy for the MFMA k_saff -----
__global__ __launch_bounds__(64) void k_E(
    const float* __restrict__ Mmat, const float* __restrict__ g,
    float* __restrict__ E, _Float16* __restrict__ E16) {
  int row = blockIdx.x;            // b*N + n
  int b = row / Nn, n = row % Nn;
  int y = n / Ww, x = n % Ww;
  int x0 = x >> 1, y0 = y >> 1;
  int x1 = min(x0 + 1, 27), y1 = min(y0 + 1, 27);
  bool hx = (x1 != x0), hy = (y1 != y0);
  int k00 = y0 * 28 + x0, k01 = y0 * 28 + x1, k10 = y1 * 28 + x0, k11 = y1 * 28 + x1;
  const float* Mr = Mmat + (size_t)n * Kk;
  float m00 = Mr[k00];
  float m01 = hx ? Mr[k01] : 0.f;
  float m10 = hy ? Mr[k10] : 0.f;
  float m11 = (hx && hy) ? Mr[k11] : 0.f;
  const float* gb = g + (size_t)b * Kk * Dd;
  int lane = threadIdx.x;
  int l2 = lane + 64;
  float a0 = m00 * gb[k00 * Dd + lane] + m01 * gb[k01 * Dd + lane] +
             m10 * gb[k10 * Dd + lane] + m11 * gb[k11 * Dd + lane];
  float a1 = m00 * gb[k00 * Dd + l2] + m01 * gb[k01 * Dd + l2] +
             m10 * gb[k10 * Dd + l2] + m11 * gb[k11 * Dd + l2];
  float ss = a0 * a0 + a1 * a1;
  for (int off = 32; off; off >>= 1) ss += __shfl_xor(ss, off);
  float inv = 1.0f / fmaxf(sqrtf(ss), 1e-6f);
  float e0 = a0 * inv, e1 = a1 * inv;
  E[(size_t)row * Dd + lane] = e0;
  E[(size_t)row * Dd + l2] = e1;
  E16[(size_t)row * Dd + lane] = (_Float16)e0;
  E16[(size_t)row * Dd + l2] = (_Float16)e1;
}

// ---- K7: Saff = (E E^T) * G -> fp16 via MFMA f16 (fp32 accum) ---------------
// 64x64 tile/block, 4 waves each a 32x32 quadrant (2x2 mfma_f32_16x16x32_f16).
// Mirror tile goes through an LDS transpose so BOTH stores are coalesced
// (the per-lane 2B row-scatter was the round-4 write-amplification bug).
__global__ __launch_bounds__(256) void k_saff(
    const _Float16* __restrict__ E16, __half* __restrict__ S) {
  int blk = blockIdx.x;
  int b = blk / 1225;
  int rem = blk % 1225;
  int ti0 = (int)((sqrtf(8.f * rem + 1.f) - 1.f) * 0.5f);
  while ((ti0 + 1) * (ti0 + 2) / 2 <= rem) ++ti0;
  while (ti0 * (ti0 + 1) / 2 > rem) --ti0;
  int tj0 = rem - ti0 * (ti0 + 1) / 2;   // tj0 <= ti0
  int i0 = ti0 * 64, j0 = tj0 * 64;
  int wave = threadIdx.x >> 6, lane = threadIdx.x & 63;
  int wr = wave >> 1, wc = wave & 1;
  int lr = lane & 15, lk = lane >> 4;    // frag row/col, k-group
  int ibase = i0 + wr * 32;
  int jbase = j0 + wc * 32;
  const _Float16* Eb = E16 + (size_t)b * Nn * Dd;
  __shared__ __half tile[64][66];        // transposed tile for mirror store
  f32x4 acc00 = {0.f, 0.f, 0.f, 0.f};
  f32x4 acc01 = acc00, acc10 = acc00, acc11 = acc00;
#pragma unroll
  for (int ks = 0; ks < 4; ++ks) {
    int ko = ks * 32 + lk * 8;
    f16x8 a0 = *reinterpret_cast<const f16x8*>(Eb + (size_t)(ibase + lr) * Dd + ko);
    f16x8 a1 = *reinterpret_cast<const f16x8*>(Eb + (size_t)(ibase + 16 + lr) * Dd + ko);
    f16x8 b0 = *reinterpret_cast<const f16x8*>(Eb + (size_t)(jbase + lr) * Dd + ko);
    f16x8 b1 = *reinterpret_cast<const f16x8*>(Eb + (size_t)(jbase + 16 + lr) * Dd + ko);
    acc00 = __builtin_amdgcn_mfma_f32_16x16x32_f16(a0, b0, acc00, 0, 0, 0);
    acc01 = __builtin_amdgcn_mfma_f32_16x16x32_f16(a0, b1, acc01, 0, 0, 0);
    acc10 = __builtin_amdgcn_mfma_f32_16x16x32_f16(a1, b0, acc10, 0, 0, 0);
    acc11 = __builtin_amdgcn_mfma_f32_16x16x32_f16(a1, b1, acc11, 0, 0, 0);
  }
  size_t ob = (size_t)b * Nn * Nn;
  int gj[2];
  float xj[2], yj[2];
#pragma unroll
  for (int tj = 0; tj < 2; ++tj) {
    gj[tj] = jbase + tj * 16 + lr;
    int yv = gj[tj] / 56;
    yj[tj] = (float)yv;
    xj[tj] = (float)(gj[tj] - yv * 56);
  }
  bool mirror = (i0 != j0);
#pragma unroll
  for (int ti = 0; ti < 2; ++ti) {
#pragma unroll
    for (int q = 0; q < 4; ++q) {
      int iloc = wr * 32 + ti * 16 + lk * 4 + q;
      int gi = i0 + iloc;
      int yiv = gi / 56;
      float yi = (float)yiv;
      float xi = (float)(gi - yiv * 56);
#pragma unroll
      for (int tj = 0; tj < 2; ++tj) {
        float a;
        if (ti == 0 && tj == 0) a = acc00[q];
        else if (ti == 0 && tj == 1) a = acc01[q];
        else if (ti == 1 && tj == 0) a = acc10[q];
        else a = acc11[q];
        float dx = xi - xj[tj];
        float dy = yi - yj[tj];
        float gg = 1.0f - __expf(-(dx * dx + dy * dy) * (1.0f / 18.0f));
        __half hv = __float2half(a * gg);
        S[ob + (size_t)gi * Nn + gj[tj]] = hv;
        int jloc = wc * 32 + tj * 16 + lr;
        tile[jloc][iloc] = hv;               // transposed stash for mirror
      }
    }
  }
  if (mirror) {
    __syncthreads();
    // coalesced mirror: 64 rows x 64 halves (128B/row) as uint stores
    for (int e = threadIdx.x; e < 64 * 32; e += 256) {
      int row = e >> 5, c2 = e & 31;
      unsigned v = *reinterpret_cast<const unsigned*>(&tile[row][c2 * 2]);
      *reinterpret_cast<unsigned*>(&S[ob + (size_t)(j0 + row) * Nn + i0 + c2 * 2]) = v;
    }
  }
}

// ---- K8: exact top-32 per row: 2-pass radix select on fp16 keys, then exact
//      fp32 recompute of the 32 selected values from E (topv/dr/dc exact) ----
__global__ __launch_bounds__(256) void k_topk(
    const __half* __restrict__ S16, const float* __restrict__ E,
    const float* __restrict__ P, float* __restrict__ topv, int* __restrict__ topi,
    float* __restrict__ dr, float* __restrict__ dc) {
  int row = blockIdx.x;
  int b = row / Nn, irow = row % Nn;
  int tid = threadIdx.x;
  const unsigned* Sr = reinterpret_cast<const unsigned*>(S16 + (size_t)row * Nn);
  __shared__ unsigned hist[256 * 8];
  __shared__ unsigned scan_s[256];
  __shared__ unsigned bcast[2];
  __shared__ unsigned sel_eq, sel_slot;
  __shared__ int sel_idx[NTOP];
  __shared__ float drow_s;
  unsigned pk[7];                  // 2 fp16 monotone keys per u32
#pragma unroll
  for (int j = 0; j < 7; ++j) {
    int c2 = tid + 256 * j;
    unsigned u = (c2 < Nn / 2) ? Sr[c2] : 0u;
    unsigned h0 = u & 0xFFFFu, h1 = u >> 16;
    unsigned k0 = h0 ^ ((h0 & 0x8000u) ? 0xFFFFu : 0x8000u);
    unsigned k1 = h1 ^ ((h1 & 0x8000u) ? 0xFFFFu : 0x8000u);
    if (c2 >= Nn / 2) { k0 = 0u; k1 = 0u; }
    pk[j] = k0 | (k1 << 16);
  }
  if (tid == 0) { sel_eq = 0; sel_slot = 0; drow_s = 0.f; }
  unsigned prefix = 0;
  unsigned k = NTOP;
  for (int pass = 0; pass < 2; ++pass) {
    int shift = 8 - 8 * pass;
    unsigned pmask = pass ? 0xFF00u : 0u;
#pragma unroll
    for (int i = 0; i < 8; ++i) hist[tid * 8 + i] = 0;
    __syncthreads();
#pragma unroll
    for (int j = 0; j < 7; ++j) {
      unsigned k0 = pk[j] & 0xFFFFu, k1 = pk[j] >> 16;
      if ((k0 & pmask) == (prefix & pmask))
        atomicAdd(&hist[((k0 >> shift) & 255u) * 8 + (tid & 7)], 1u);
      if ((k1 & pmask) == (prefix & pmask))
        atomicAdd(&hist[((k1 >> shift) & 255u) * 8 + (tid & 7)], 1u);
    }
    __syncthreads();
    unsigned cnt = 0;
#pragma unroll
    for (int i = 0; i < 8; ++i) cnt += hist[tid * 8 + i];
    unsigned run = cnt;
    scan_s[tid] = run;
    for (int st = 1; st < 256; st <<= 1) {
      __syncthreads();
      unsigned add = (tid + st < 256) ? scan_s[tid + st] : 0u;
      __syncthreads();
      run += add;
      scan_s[tid] = run;
    }
    unsigned incl = run;
    unsigned excl = incl - cnt;
    if (excl < k && k <= incl) {
      bcast[0] = prefix | ((unsigned)tid << shift);
      bcast[1] = k - excl;
    }
    __syncthreads();
    prefix = bcast[0];
    k = bcast[1];
    __syncthreads();
  }
  unsigned T = prefix;
#pragma unroll
  for (int j = 0; j < 7; ++j) {
    int c2 = tid + 256 * j;
    if (c2 < Nn / 2) {
      unsigned k0 = pk[j] & 0xFFFFu, k1 = pk[j] >> 16;
      bool take0 = (k0 > T) || (k0 == T && atomicAdd(&sel_eq, 1u) < k);
      if (take0) { unsigned slot = atomicAdd(&sel_slot, 1u); sel_idx[slot] = 2 * c2; }
      bool take1 = (k1 > T) || (k1 == T && atomicAdd(&sel_eq, 1u) < k);
      if (take1) { unsigned slot = atomicAdd(&sel_slot, 1u); sel_idx[slot] = 2 * c2 + 1; }
    }
  }
  __syncthreads();
  // exact recompute: 8 threads per selected entry
  int sel = tid >> 3, part = tid & 7;
  int col = sel_idx[sel];
  const float* Ei = E + ((size_t)b * Nn + irow) * Dd;
  const float* Ej = E + ((size_t)b * Nn + col) * Dd;
  float v = 0.f;
#pragma unroll
  for (int d0 = 0; d0 < 16; ++d0) {
    int d = part * 16 + d0;
    v += Ei[d] * Ej[d];
  }
  v += __shfl_xor(v, 1);
  v += __shfl_xor(v, 2);
  v += __shfl_xor(v, 4);
  if (part == 0) {
    float dx = P[irow * 2] - P[col * 2];
    float dy = P[irow * 2 + 1] - P[col * 2 + 1];
    float gg = 1.0f - __expf(-(dx * dx + dy * dy) * (1.0f / 18.0f));
    v *= gg;
    topv[(size_t)row * NTOP + sel] = v;
    topi[(size_t)row * NTOP + sel] = col;
    float e = __expf(10.f * v);
    atomicAdd(&dc[b * Nn + col], e - 1.f);
    atomicAdd(&drow_s, e);
  }
  __syncthreads();
  if (tid == 0) dr[row] = (float)(Nn - NTOP) + drow_s;
}

__global__ void k_dcinit(float* __restrict__ dc) {
  int i = blockIdx.x * 256 + threadIdx.x;
  if (i < Bb * Nn) dc[i] = (float)Nn;
}

__global__ void k_inv(float* __restrict__ dr, float* __restrict__ dc) {
  int i = blockIdx.x * 256 + threadIdx.x;
  if (i < Bb * Nn) {
    dr[i] = 1.0f / dr[i];
    dc[i] = 1.0f / dc[i];
  }
}

// ---------------- K10: A0 row = invdr_i * invdc_j, then fix 32 entries -------
__global__ __launch_bounds__(256) void k_basefix(
    const float* __restrict__ invdr, const float* __restrict__ invdc,
    const float* __restrict__ topv, const int* __restrict__ topi,
    float* __restrict__ A0) {
  int row = blockIdx.x;            // b*N + i
  int b = row / Nn;
  float idr = invdr[row];
  const float4* dc4 = reinterpret_cast<const float4*>(invdc + b * Nn);
  float4* out4 = reinterpret_cast<float4*>(A0 + (size_t)row * Nn);
  for (int j = threadIdx.x; j < Nn / 4; j += 256) {
    float4 c = dc4[j];
    float4 o = {idr * c.x, idr * c.y, idr * c.z, idr * c.w};
    out4[j] = o;
  }
  __syncthreads();
  if (threadIdx.x < NTOP) {
    int gidx = row * NTOP + threadIdx.x;
    int col = topi[gidx];
    float e = __expf(10.f * topv[gidx]);
    A0[(size_t)row * Nn + col] = e * e * idr * invdc[b * Nn + col];
  }
}

extern "C" void kernel_launch(void* const* d_in, const int* in_sizes, int n_in,
                              void* d_out, int out_size, void* d_ws, size_t ws_size,
                              hipStream_t stream) {
  const float* fm     = (const float*)d_in[0];
  const float* Abank  = (const float*)d_in[1];
  const float* pw_w   = (const float*)d_in[2];
  const float* pw_b   = (const float*)d_in[3];
  const float* proj_w = (const float*)d_in[4];
  const float* proj_b = (const float*)d_in[5];
  const float* r      = (const float*)d_in[6];
  const float* Mmat   = (const float*)d_in[7];
  const float* P      = (const float*)d_in[8];
  float* out = (float*)d_out;
  float* E  = out;
  float* A0 = out + (size_t)Bb * Nn * Dd;
  // fp16 S aliases into the A0 output region (read fully by k_topk before
  // k_basefix overwrites A0) — zero extra workspace.
  __half* S16 = (__half*)A0;

  float* ws = (float*)d_ws;
  float* y     = ws;                       //  1,605,632 floats (B*64*N*2, pair-interleaved)
  float* zt    = ws + 1605632;             //  6,422,528 (T*B*D*K, d-major)
  float* z     = ws + 8028160;             //  6,422,528 (T*B*K*D, normalized)
  float* wct   = ws + 14450688;            //     32,768
  float* bcv   = ws + 14483456;            //        128
  float* s_arr = ws + 14483584;            //     50,176
  float* g     = ws + 14533760;            //    401,408
  float* topv  = ws + 14935168;            //    401,408
  int*   topi  = (int*)(ws + 15336576);    //    401,408
  float* dr    = ws + 15737984;            //     12,544
  float* dc    = ws + 15750528;            //     12,544
  _Float16* E16 = (_Float16*)(ws + 15763072); // 1,605,632 halves

  hipLaunchKernelGGL(k_wc, dim3(Cc), dim3(128), 0, stream, pw_w, pw_b, proj_w, proj_b, wct, bcv);
  hipLaunchKernelGGL(k_mix, dim3(448), dim3(256), 0, stream, fm, wct, y);
  hipLaunchKernelGGL(k_fused_pool, dim3(2048), dim3(256), 0, stream, y, Abank, bcv, zt);
  hipLaunchKernelGGL(k_znorm, dim3(64 * 14), dim3(256), 0, stream, zt, r, z, s_arr);
  hipLaunchKernelGGL(k_gemb, dim3(Bb * Kk), dim3(128), 0, stream, z, s_arr, g);
  hipLaunchKernelGGL(k_E, dim3(Bb * Nn), dim3(64), 0, stream, Mmat, g, E, E16);
  hipLaunchKernelGGL(k_saff, dim3(Bb * 1225), dim3(256), 0, stream, E16, S16);
  hipLaunchKernelGGL(k_dcinit, dim3(49), dim3(256), 0, stream, dc);
  hipLaunchKernelGGL(k_topk, dim3(Bb * Nn), dim3(256), 0, stream, S16, E, P, topv, topi, dr, dc);
  hipLaunchKernelGGL(k_inv, dim3(49), dim3(256), 0, stream, dr, dc);
  hipLaunchKernelGGL(k_basefix, dim3(Bb * Nn), dim3(256), 0, stream, dr, dc, topv, topi, A0);
}

// Round 6
// 427.043 us; speedup vs baseline: 1.6331x; 1.0220x over previous
//
#include <hip/hip_runtime.h>
#include <hip/hip_bf16.h>
#include <hip/hip_fp16.h>

#define Hh 56
#define Ww 56
#define Cc 256
#define Tt 16
#define Bb 4
#define Nn 3136
#define Kk 784
#define KX 28
#define Dd 128
#define Mc 64
#define NTOP 32

typedef __attribute__((ext_vector_type(8))) _Float16 f16x8;
typedef __attribute__((ext_vector_type(4))) float f32x4;

// ---------------- K3a: combined weight Wc^T [c][d] and bias bc ---------------
__global__ __launch_bounds__(128) void k_wc(
    const float* __restrict__ pw_w, const float* __restrict__ pw_b,
    const float* __restrict__ proj_w, const float* __restrict__ proj_b,
    float* __restrict__ wct, float* __restrict__ bc) {
  int c = blockIdx.x;
  int d = threadIdx.x;
  float acc = 0.f;
  for (int m = 0; m < Mc; ++m) acc += proj_w[d * Mc + m] * pw_w[m * Cc + c];
  wct[c * Dd + d] = acc;
  if (c == 0) {
    float bb = proj_b[d];
    for (int m = 0; m < Mc; ++m) bb += proj_w[d * Mc + m] * pw_b[m];
    bc[d] = bb;
  }
}

// ---- K_coords: per-t warp taps precomputed ONCE (was redone in 2048 blocks) -
__global__ __launch_bounds__(256) void k_coords(
    const float* __restrict__ Abank, unsigned* __restrict__ offo,
    float2* __restrict__ wo) {
  int t = blockIdx.x;
  const float* A = Abank + t * 6;
  float a00 = A[0], a01 = A[1], a02 = A[2], a10 = A[3], a11 = A[4], a12 = A[5];
  for (int e = threadIdx.x; e < Nn; e += 256) {
    int h = e / 56, w = e - h * 56;
    float gx = (2.0f * w + 1.0f) / 56.0f - 1.0f;
    float gy = (2.0f * h + 1.0f) / 56.0f - 1.0f;
    float u = a00 * gx + a01 * gy + a02;
    float v = a10 * gx + a11 * gy + a12;
    float ix = ((u + 1.0f) * 56.0f - 1.0f) * 0.5f;
    float iy = ((v + 1.0f) * 56.0f - 1.0f) * 0.5f;
    float x0f = floorf(ix), y0f = floorf(iy);
    int x0 = (int)x0f, y0 = (int)y0f;
    int x0c = min(max(x0, 0), 55), x1c = min(max(x0 + 1, 0), 55);
    int y0c = min(max(y0, 0), 55), y1c = min(max(y0 + 1, 0), 55);
    offo[t * Nn + e] = (y0c * 56 + x0c) | ((x1c - x0c) << 12) | ((y1c - y0c) << 13);
    float2 wv2;
    wv2.x = ix - x0f;
    wv2.y = iy - y0f;
    wo[t * Nn + e] = wv2;
  }
}

// ---- K_mix: channel mix FIRST, pair-interleaved output. b128 LDS reads ------
// grid: b(4) x ntile(98 of 32) = 392 blocks, 256 thr
__global__ __launch_bounds__(256) void k_mix(
    const float* __restrict__ fm, const float* __restrict__ wct, float* __restrict__ y) {
  int blk = blockIdx.x;
  int b = blk / 98;
  int n0 = (blk % 98) * 32;
  int tid = threadIdx.x;
  int d = tid & 127;
  int ng = tid >> 7;               // 0..1 -> k-half of 16
  __shared__ __align__(16) float fm_s[64][32];
  __shared__ float wc_s[64 * Dd];
  float acc[16];
#pragma unroll
  for (int j = 0; j < 16; ++j) acc[j] = 0.f;
  const float* fb = fm + (size_t)b * Cc * Nn;
  for (int c0 = 0; c0 < Cc; c0 += 64) {
    for (int i = tid; i < 64 * 32; i += 256) {
      int c = i >> 5, kx = i & 31;
      fm_s[c][kx] = fb[(size_t)(c0 + c) * Nn + n0 + kx];
    }
    for (int i = tid; i < 64 * Dd; i += 256) wc_s[i] = wct[c0 * Dd + i];
    __syncthreads();
    for (int c = 0; c < 64; ++c) {
      float w = wc_s[c * Dd + d];
      const float4* fr = reinterpret_cast<const float4*>(&fm_s[c][ng * 16]);
      float4 f0 = fr[0], f1 = fr[1], f2 = fr[2], f3 = fr[3];
      acc[0]  += f0.x * w; acc[1]  += f0.y * w; acc[2]  += f0.z * w; acc[3]  += f0.w * w;
      acc[4]  += f1.x * w; acc[5]  += f1.y * w; acc[6]  += f1.z * w; acc[7]  += f1.w * w;
      acc[8]  += f2.x * w; acc[9]  += f2.y * w; acc[10] += f2.z * w; acc[11] += f2.w * w;
      acc[12] += f3.x * w; acc[13] += f3.y * w; acc[14] += f3.z * w; acc[15] += f3.w * w;
    }
    __syncthreads();
  }
  size_t base = (((size_t)b * 64 + (d >> 1)) * Nn + n0 + ng * 16) * 2 + (d & 1);
#pragma unroll
  for (int j = 0; j < 16; ++j) y[base + 2 * j] = acc[j];
}

// ---- K1: fused warp+bilinear+9x9/s2 pool, 2 channels at a time via float2 ---
// grid: b(4) x pg(32, 2 pairs each) x t(16) = 2048 blocks, 256 thr
// Taps come from k_coords tables (no per-block coordinate math).
__global__ __launch_bounds__(256) void k_fused_pool(
    const float* __restrict__ yraw, const unsigned* __restrict__ offo,
    const float2* __restrict__ wo, const float* __restrict__ bc,
    float* __restrict__ zt) {
  const float2* y2 = reinterpret_cast<const float2*>(yraw);
  int idx = blockIdx.x;
  int b = idx & 3;
  int pg = (idx >> 2) & 31;
  int t = idx >> 7;
  __shared__ float2 wsm[3136];
  __shared__ float2 rowp[1568];
  int tid = threadIdx.x;
  const unsigned* offp = offo + t * Nn;
  const float2* wp = wo + t * Nn;
  unsigned off[13];
  float2 wv[13];
#pragma unroll
  for (int j = 0; j < 13; ++j) {
    int e = tid + 256 * j;
    if (e < 3136) {
      off[j] = offp[e];
      wv[j] = wp[e];
    }
  }
  for (int pp = 0; pp < 2; ++pp) {
    int dp = pg * 2 + pp;                       // channel pair 0..63
    const float2* fc = y2 + ((size_t)b * 64 + dp) * Nn;
    float b0 = bc[dp * 2], b1 = bc[dp * 2 + 1];
#pragma unroll
    for (int j = 0; j < 13; ++j) {
      int e = tid + 256 * j;
      if (e < 3136) {
        unsigned pk = off[j];
        int base = pk & 4095;
        int dx = (pk >> 12) & 1;
        int dyy = (pk & (1u << 13)) ? 56 : 0;
        float2 v00 = fc[base], v01 = fc[base + dx];
        float2 v10 = fc[base + dyy], v11 = fc[base + dyy + dx];
        float wx = wv[j].x, wy = wv[j].y;
        float tx = v00.x + wx * (v01.x - v00.x);
        float bx = v10.x + wx * (v11.x - v10.x);
        float ty = v00.y + wx * (v01.y - v00.y);
        float by = v10.y + wx * (v11.y - v10.y);
        float2 o;
        o.x = tx + wy * (bx - tx);
        o.y = ty + wy * (by - ty);
        wsm[e] = o;
      }
    }
    __syncthreads();
    for (int e = tid; e < 1568; e += 256) {
      int h = e / 28, kx = e - h * 28;
      int xs = 2 * kx - 4;
      int lo = max(xs, 0), hi = min(xs + 8, 55);
      float sx = 0.f, sy = 0.f;
      const float2* wr = wsm + h * 56;
      for (int x = lo; x <= hi; ++x) { float2 v = wr[x]; sx += v.x; sy += v.y; }
      float2 o; o.x = sx; o.y = sy;
      rowp[e] = o;
    }
    __syncthreads();
    float* zo0 = zt + ((size_t)(t * Bb + b) * Dd + dp * 2) * Kk;
    float* zo1 = zo0 + Kk;
    for (int e = tid; e < 784; e += 256) {
      int ky = e / 28, kx = e - ky * 28;
      int ys = 2 * ky - 4;
      int lo = max(ys, 0), hi = min(ys + 8, 55);
      float sx = 0.f, sy = 0.f;
      for (int h = lo; h <= hi; ++h) { float2 rv = rowp[h * 28 + kx]; sx += rv.x; sy += rv.y; }
      zo0[e] = sx * (1.0f / 81.0f) + b0;
      zo1[e] = sy * (1.0f / 81.0f) + b1;
    }
    __syncthreads();
  }
}

// ---- K4: transpose zt -> z (normalized, [tb][k][d]) + s = zn . r ------------
__global__ __launch_bounds__(256) void k_znorm(
    const float* __restrict__ zt, const float* __restrict__ r,
    float* __restrict__ z, float* __restrict__ s_arr) {
  int tb = blockIdx.x / 14;
  int k0 = (blockIdx.x % 14) * 56;
  int tid = threadIdx.x;
  __shared__ float ls[56 * 129];
  const float* zb = zt + (size_t)tb * Dd * Kk + k0;
  for (int i = tid; i < Dd * 56; i += 256) {
    int d = i / 56, kk = i - d * 56;
    ls[kk * 129 + d] = zb[(size_t)d * Kk + kk];
  }
  int lane = tid & 63;
  int wvv = tid >> 6;              // 0..3
  float r0 = r[lane], r1 = r[lane + 64];
  __syncthreads();
  for (int p = 0; p < 14; ++p) {
    int k = p * 4 + wvv;
    float z0 = ls[k * 129 + lane];
    float z1 = ls[k * 129 + 64 + lane];
    float ss = z0 * z0 + z1 * z1;
    for (int off = 32; off; off >>= 1) ss += __shfl_xor(ss, off);
    float inv = 1.0f / fmaxf(sqrtf(ss), 1e-6f);
    z0 *= inv; z1 *= inv;
    float* zr = z + ((size_t)tb * Kk + k0 + k) * Dd;
    zr[lane] = z0;
    zr[lane + 64] = z1;
    float sd = z0 * r0 + z1 * r1;
    for (int off = 32; off; off >>= 1) sd += __shfl_xor(sd, off);
    if (lane == 0) s_arr[(size_t)tb * Kk + k0 + k] = sd;
  }
}

// ---------------- K5: softmax over T, g_emb ----------------------------------
__global__ __launch_bounds__(128) void k_gemb(
    const float* __restrict__ z, const float* __restrict__ s_arr, float* __restrict__ g) {
  int blk = blockIdx.x;            // b*784 + k
  int b = blk / Kk, k = blk % Kk;
  int d = threadIdx.x;
  float sv[Tt];
  float mx = -3.4e38f;
#pragma unroll
  for (int t = 0; t < Tt; ++t) {
    sv[t] = s_arr[(t * Bb + b) * Kk + k];
    mx = fmaxf(mx, sv[t]);
  }
  float sum = 0.f;
#pragma unroll
  for (int t = 0; t < Tt; ++t) {
    sv[t] = expf(10.0f * (sv[t] - mx));
    sum += sv[t];
  }
  float isum = 1.0f / sum;
  float acc = 0.f;
#pragma unroll
  for (int t = 0; t < Tt; ++t)
    acc += sv[t] * isum * z[((size_t)(t * Bb + b) * Kk + k) * Dd + d];
  g[((size_t)b * Kk + k) * Dd + d] = acc;
}

// ---- K6: E = normalize(M @ g), also emits fp16 copy. 2 rows per block -------
__global__ __launch_bounds__(128) void k_E(
    const float* __restrict__ Mmat, const float* __restrict__ g,
    float* __restrict__ E, _Float16* __restrict__ E16) {
  int row = blockIdx.x * 2 + (threadIdx.x >> 6);   // b*N + n
  int b = row / Nn, n = row % Nn;
  int y = n / Ww, x = n % Ww;
  int x0 = x >> 1, y0 = y >> 1;
  int x1 = min(x0 + 1, 27), y1 = min(y0 + 1, 27);
  bool hx = (x1 != x0), hy = (y1 != y0);
  int k00 = y0 * 28 + x0, k01 = y0 * 28 + x1, k10 = y1 * 28 + x0, k11 = y1 * 28 + x1;
  const float* Mr = Mmat + (size_t)n * Kk;
  float m00 = Mr[k00];
  float m01 = hx ? Mr[k01] : 0.f;
  float m10 = hy ? Mr[k10] : 0.f;
  float m11 = (hx && hy) ? Mr[k11] : 0.f;
  const float* gb = g + (size_t)b * Kk * Dd;
  int lane = threadIdx.x & 63;
  int l2 = lane + 64;
  float a0 = m00 * gb[k00 * Dd + lane] + m01 * gb[k01 * Dd + lane] +
             m10 * gb[k10 * Dd + lane] + m11 * gb[k11 * Dd + lane];
  float a1 = m00 * gb[k00 * Dd + l2] + m01 * gb[k01 * Dd + l2] +
             m10 * gb[k10 * Dd + l2] + m11 * gb[k11 * Dd + l2];
  float ss = a0 * a0 + a1 * a1;
  for (int off = 32; off; off >>= 1) ss += __shfl_xor(ss, off);
  float inv = 1.0f / fmaxf(sqrtf(ss), 1e-6f);
  float e0 = a0 * inv, e1 = a1 * inv;
  E[(size_t)row * Dd + lane] = e0;
  E[(size_t)row * Dd + l2] = e1;
  E16[(size_t)row * Dd + lane] = (_Float16)e0;
  E16[(size_t)row * Dd + l2] = (_Float16)e1;
}

// ---- K7: Saff = (E E^T) * G -> fp16 via MFMA f16 (fp32 accum) ---------------
__global__ __launch_bounds__(256) void k_saff(
    const _Float16* __restrict__ E16, __half* __restrict__ S) {
  int blk = blockIdx.x;
  int b = blk / 1225;
  int rem = blk % 1225;
  int ti0 = (int)((sqrtf(8.f * rem + 1.f) - 1.f) * 0.5f);
  while ((ti0 + 1) * (ti0 + 2) / 2 <= rem) ++ti0;
  while (ti0 * (ti0 + 1) / 2 > rem) --ti0;
  int tj0 = rem - ti0 * (ti0 + 1) / 2;   // tj0 <= ti0
  int i0 = ti0 * 64, j0 = tj0 * 64;
  int wave = threadIdx.x >> 6, lane = threadIdx.x & 63;
  int wr = wave >> 1, wc = wave & 1;
  int lr = lane & 15, lk = lane >> 4;    // frag row/col, k-group
  int ibase = i0 + wr * 32;
  int jbase = j0 + wc * 32;
  const _Float16* Eb = E16 + (size_t)b * Nn * Dd;
  __shared__ __half tile[64][66];        // transposed tile for mirror store
  f32x4 acc00 = {0.f, 0.f, 0.f, 0.f};
  f32x4 acc01 = acc00, acc10 = acc00, acc11 = acc00;
#pragma unroll
  for (int ks = 0; ks < 4; ++ks) {
    int ko = ks * 32 + lk * 8;
    f16x8 a0 = *reinterpret_cast<const f16x8*>(Eb + (size_t)(ibase + lr) * Dd + ko);
    f16x8 a1 = *reinterpret_cast<const f16x8*>(Eb + (size_t)(ibase + 16 + lr) * Dd + ko);
    f16x8 b0 = *reinterpret_cast<const f16x8*>(Eb + (size_t)(jbase + lr) * Dd + ko);
    f16x8 b1 = *reinterpret_cast<const f16x8*>(Eb + (size_t)(jbase + 16 + lr) * Dd + ko);
    acc00 = __builtin_amdgcn_mfma_f32_16x16x32_f16(a0, b0, acc00, 0, 0, 0);
    acc01 = __builtin_amdgcn_mfma_f32_16x16x32_f16(a0, b1, acc01, 0, 0, 0);
    acc10 = __builtin_amdgcn_mfma_f32_16x16x32_f16(a1, b0, acc10, 0, 0, 0);
    acc11 = __builtin_amdgcn_mfma_f32_16x16x32_f16(a1, b1, acc11, 0, 0, 0);
  }
  size_t ob = (size_t)b * Nn * Nn;
  int gj[2];
  float xj[2], yj[2];
#pragma unroll
  for (int tj = 0; tj < 2; ++tj) {
    gj[tj] = jbase + tj * 16 + lr;
    int yv = gj[tj] / 56;
    yj[tj] = (float)yv;
    xj[tj] = (float)(gj[tj] - yv * 56);
  }
  bool mirror = (i0 != j0);
#pragma unroll
  for (int ti = 0; ti < 2; ++ti) {
#pragma unroll
    for (int q = 0; q < 4; ++q) {
      int iloc = wr * 32 + ti * 16 + lk * 4 + q;
      int gi = i0 + iloc;
      int yiv = gi / 56;
      float yi = (float)yiv;
      float xi = (float)(gi - yiv * 56);
#pragma unroll
      for (int tj = 0; tj < 2; ++tj) {
        float a;
        if (ti == 0 && tj == 0) a = acc00[q];
        else if (ti == 0 && tj == 1) a = acc01[q];
        else if (ti == 1 && tj == 0) a = acc10[q];
        else a = acc11[q];
        float dx = xi - xj[tj];
        float dy = yi - yj[tj];
        float gg = 1.0f - __expf(-(dx * dx + dy * dy) * (1.0f / 18.0f));
        __half hv = __float2half(a * gg);
        S[ob + (size_t)gi * Nn + gj[tj]] = hv;
        int jloc = wc * 32 + tj * 16 + lr;
        tile[jloc][iloc] = hv;               // transposed stash for mirror
      }
    }
  }
  if (mirror) {
    __syncthreads();
    for (int e = threadIdx.x; e < 64 * 32; e += 256) {
      int row = e >> 5, c2 = e & 31;
      unsigned v = *reinterpret_cast<const unsigned*>(&tile[row][c2 * 2]);
      *reinterpret_cast<unsigned*>(&S[ob + (size_t)(j0 + row) * Nn + i0 + c2 * 2]) = v;
    }
  }
}

// ---- K8: exact top-32 per row: 2-pass radix select on fp16 keys (wave-scan),
//      then exact fp32 recompute of the 32 selected values from E ------------
__global__ __launch_bounds__(256) void k_topk(
    const __half* __restrict__ S16, const float* __restrict__ E,
    const float* __restrict__ P, float* __restrict__ topv, int* __restrict__ topi,
    float* __restrict__ dr, float* __restrict__ dc) {
  int row = blockIdx.x;
  int b = row / Nn, irow = row % Nn;
  int tid = threadIdx.x;
  const unsigned* Sr = reinterpret_cast<const unsigned*>(S16 + (size_t)row * Nn);
  __shared__ unsigned hist[256 * 8];
  __shared__ unsigned wtot[4];
  __shared__ unsigned bcast[2];
  __shared__ unsigned sel_eq, sel_slot;
  __shared__ int sel_idx[NTOP];
  __shared__ float drow_s;
  unsigned pk[7];                  // 2 fp16 monotone keys per u32
#pragma unroll
  for (int j = 0; j < 7; ++j) {
    int c2 = tid + 256 * j;
    unsigned u = (c2 < Nn / 2) ? Sr[c2] : 0u;
    unsigned h0 = u & 0xFFFFu, h1 = u >> 16;
    unsigned k0 = h0 ^ ((h0 & 0x8000u) ? 0xFFFFu : 0x8000u);
    unsigned k1 = h1 ^ ((h1 & 0x8000u) ? 0xFFFFu : 0x8000u);
    if (c2 >= Nn / 2) { k0 = 0u; k1 = 0u; }
    pk[j] = k0 | (k1 << 16);
  }
  if (tid == 0) { sel_eq = 0; sel_slot = 0; drow_s = 0.f; }
  int lane = tid & 63, wvq = tid >> 6;
  unsigned prefix = 0;
  unsigned k = NTOP;
  for (int pass = 0; pass < 2; ++pass) {
    int shift = 8 - 8 * pass;
    unsigned pmask = pass ? 0xFF00u : 0u;
#pragma unroll
    for (int i = 0; i < 8; ++i) hist[tid * 8 + i] = 0;
    __syncthreads();
#pragma unroll
    for (int j = 0; j < 7; ++j) {
      unsigned k0 = pk[j] & 0xFFFFu, k1 = pk[j] >> 16;
      if ((k0 & pmask) == (prefix & pmask))
        atomicAdd(&hist[((k0 >> shift) & 255u) * 8 + (tid & 7)], 1u);
      if ((k1 & pmask) == (prefix & pmask))
        atomicAdd(&hist[((k1 >> shift) & 255u) * 8 + (tid & 7)], 1u);
    }
    __syncthreads();
    unsigned cnt = 0;
#pragma unroll
    for (int i = 0; i < 8; ++i) cnt += hist[tid * 8 + i];
    // reverse inclusive scan (sum over buckets >= tid) via wave shfl, no LDS ladder
    unsigned run = cnt;
#pragma unroll
    for (int off2 = 1; off2 < 64; off2 <<= 1) {
      unsigned v = __shfl_down(run, off2);
      if (lane + off2 < 64) run += v;
    }
    if (lane == 0) wtot[wvq] = run;  // wave total
    __syncthreads();
    unsigned hi = 0;
    for (int w2 = wvq + 1; w2 < 4; ++w2) hi += wtot[w2];
    unsigned incl = run + hi;
    unsigned excl = incl - cnt;
    if (excl < k && k <= incl) {
      bcast[0] = prefix | ((unsigned)tid << shift);
      bcast[1] = k - excl;
    }
    __syncthreads();
    prefix = bcast[0];
    k = bcast[1];
    __syncthreads();
  }
  unsigned T = prefix;
#pragma unroll
  for (int j = 0; j < 7; ++j) {
    int c2 = tid + 256 * j;
    if (c2 < Nn / 2) {
      unsigned k0 = pk[j] & 0xFFFFu, k1 = pk[j] >> 16;
      bool take0 = (k0 > T) || (k0 == T && atomicAdd(&sel_eq, 1u) < k);
      if (take0) { unsigned slot = atomicAdd(&sel_slot, 1u); sel_idx[slot] = 2 * c2; }
      bool take1 = (k1 > T) || (k1 == T && atomicAdd(&sel_eq, 1u) < k);
      if (take1) { unsigned slot = atomicAdd(&sel_slot, 1u); sel_idx[slot] = 2 * c2 + 1; }
    }
  }
  __syncthreads();
  // exact recompute: 8 threads per selected entry
  int sel = tid >> 3, part = tid & 7;
  int col = sel_idx[sel];
  const float* Ei = E + ((size_t)b * Nn + irow) * Dd;
  const float* Ej = E + ((size_t)b * Nn + col) * Dd;
  float v = 0.f;
#pragma unroll
  for (int d0 = 0; d0 < 16; ++d0) {
    int d = part * 16 + d0;
    v += Ei[d] * Ej[d];
  }
  v += __shfl_xor(v, 1);
  v += __shfl_xor(v, 2);
  v += __shfl_xor(v, 4);
  if (part == 0) {
    float dx = P[irow * 2] - P[col * 2];
    float dy = P[irow * 2 + 1] - P[col * 2 + 1];
    float gg = 1.0f - __expf(-(dx * dx + dy * dy) * (1.0f / 18.0f));
    v *= gg;
    topv[(size_t)row * NTOP + sel] = v;
    topi[(size_t)row * NTOP + sel] = col;
    float e = __expf(10.f * v);
    atomicAdd(&dc[b * Nn + col], e - 1.f);
    atomicAdd(&drow_s, e);
  }
  __syncthreads();
  if (tid == 0) dr[row] = (float)(Nn - NTOP) + drow_s;
}

__global__ void k_dcinit(float* __restrict__ dc) {
  int i = blockIdx.x * 256 + threadIdx.x;
  if (i < Bb * Nn) dc[i] = (float)Nn;
}

__global__ void k_inv(float* __restrict__ dr, float* __restrict__ dc) {
  int i = blockIdx.x * 256 + threadIdx.x;
  if (i < Bb * Nn) {
    dr[i] = 1.0f / dr[i];
    dc[i] = 1.0f / dc[i];
  }
}

// ---------------- K10: A0 row = invdr_i * invdc_j, then fix 32 entries -------
__global__ __launch_bounds__(256) void k_basefix(
    const float* __restrict__ invdr, const float* __restrict__ invdc,
    const float* __restrict__ topv, const int* __restrict__ topi,
    float* __restrict__ A0) {
  int row = blockIdx.x;            // b*N + i
  int b = row / Nn;
  float idr = invdr[row];
  const float4* dc4 = reinterpret_cast<const float4*>(invdc + b * Nn);
  float4* out4 = reinterpret_cast<float4*>(A0 + (size_t)row * Nn);
  for (int j = threadIdx.x; j < Nn / 4; j += 256) {
    float4 c = dc4[j];
    float4 o = {idr * c.x, idr * c.y, idr * c.z, idr * c.w};
    out4[j] = o;
  }
  __syncthreads();
  if (threadIdx.x < NTOP) {
    int gidx = row * NTOP + threadIdx.x;
    int col = topi[gidx];
    float e = __expf(10.f * topv[gidx]);
    A0[(size_t)row * Nn + col] = e * e * idr * invdc[b * Nn + col];
  }
}

extern "C" void kernel_launch(void* const* d_in, const int* in_sizes, int n_in,
                              void* d_out, int out_size, void* d_ws, size_t ws_size,
                              hipStream_t stream) {
  const float* fm     = (const float*)d_in[0];
  const float* Abank  = (const float*)d_in[1];
  const float* pw_w   = (const float*)d_in[2];
  const float* pw_b   = (const float*)d_in[3];
  const float* proj_w = (const float*)d_in[4];
  const float* proj_b = (const float*)d_in[5];
  const float* r      = (const float*)d_in[6];
  const float* Mmat   = (const float*)d_in[7];
  const float* P      = (const float*)d_in[8];
  float* out = (float*)d_out;
  float* E  = out;
  float* A0 = out + (size_t)Bb * Nn * Dd;
  // fp16 S aliases into the A0 output region (read fully by k_topk before
  // k_basefix overwrites A0) — zero extra workspace.
  __half* S16 = (__half*)A0;

  float* ws = (float*)d_ws;
  float* y     = ws;                       //  1,605,632 floats (B*64*N*2, pair-interleaved)
  float* zt    = ws + 1605632;             //  6,422,528 (T*B*D*K, d-major)
  float* z     = ws + 8028160;             //  6,422,528 (T*B*K*D, normalized)
  float* wct   = ws + 14450688;            //     32,768
  float* bcv   = ws + 14483456;            //        128
  float* s_arr = ws + 14483584;            //     50,176
  float* g     = ws + 14533760;            //    401,408
  float* topv  = ws + 14935168;            //    401,408
  int*   topi  = (int*)(ws + 15336576);    //    401,408
  float* dr    = ws + 15737984;            //     12,544
  float* dc    = ws + 15750528;            //     12,544
  _Float16* E16 = (_Float16*)(ws + 15763072);   // 802,816 floats worth
  unsigned* offo = (unsigned*)(ws + 16565888);  // 50,176 u32 (T*N taps)
  float2*   wo   = (float2*)(ws + 16616064);    // 50,176 float2

  hipLaunchKernelGGL(k_wc, dim3(Cc), dim3(128), 0, stream, pw_w, pw_b, proj_w, proj_b, wct, bcv);
  hipLaunchKernelGGL(k_coords, dim3(Tt), dim3(256), 0, stream, Abank, offo, wo);
  hipLaunchKernelGGL(k_mix, dim3(392), dim3(256), 0, stream, fm, wct, y);
  hipLaunchKernelGGL(k_fused_pool, dim3(2048), dim3(256), 0, stream, y, offo, wo, bcv, zt);
  hipLaunchKernelGGL(k_znorm, dim3(64 * 14), dim3(256), 0, stream, zt, r, z, s_arr);
  hipLaunchKernelGGL(k_gemb, dim3(Bb * Kk), dim3(128), 0, stream, z, s_arr, g);
  hipLaunchKernelGGL(k_E, dim3(Bb * Nn / 2), dim3(128), 0, stream, Mmat, g, E, E16);
  hipLaunchKernelGGL(k_saff, dim3(Bb * 1225), dim3(256), 0, stream, E16, S16);
  hipLaunchKernelGGL(k_dcinit, dim3(49), dim3(256), 0, stream, dc);
  hipLaunchKernelGGL(k_topk, dim3(Bb * Nn), dim3(256), 0, stream, S16, E, P, topv, topi, dr, dc);
  hipLaunchKernelGGL(k_inv, dim3(49), dim3(256), 0, stream, dr, dc);
  hipLaunchKernelGGL(k_basefix, dim3(Bb * Nn), dim3(256), 0, stream, dr, dc, topv, topi, A0);
}